// Round 11
// baseline (1805.446 us; speedup 1.0000x reference)
//
#include <hip/hip_runtime.h>
#include <math.h>

#define BATCH 512
#define NG 16
#define GSZ 32
#define H 128
#define E 64
#define PRE 512
#define BOT 1024
#define MLPD 1024
#define SEQ 12
#define AK 1152   // Abf row length = H + BOT
#define NBLK 256  // persistent grid size (1 block/CU nominal; co-residency by capacity)

typedef __attribute__((ext_vector_type(8))) short bf16x8;
typedef __attribute__((ext_vector_type(4))) float f32x4;

union bf8pack { ushort s[8]; uint4 v; };

__device__ __forceinline__ unsigned short f2bf(float f) {
    unsigned u = __float_as_uint(f);
    u += 0x7FFF + ((u >> 16) & 1);   // round-to-nearest-even
    return (unsigned short)(u >> 16);
}

#define GLB(p) ((const __attribute__((address_space(1))) unsigned int*)(p))
#define LDS(p) ((__attribute__((address_space(3))) unsigned int*)(p))

// ---------------------------------------------------------------- one-shot prep
#define N0 (BOT * PRE)        /* W2pk: MFMA-fragment-packed W2 (R9) */
#define N1 (MLPD * AK)        /* Wm1pk: MFMA-fragment-packed Wm1 (R10) */
#define N2 (H * MLPD)         /* Wm2pk: MFMA-fragment-packed Wm2 (R10) */
#define N3 (PRE * H)          /* W1pk: MFMA-fragment-packed W1[:,64:192] (R4) */
#define N4 (PRE)              /* wc    */
#define N5 (BATCH * H)        /* c     */
#define N5b (BATCH * H)       /* h0 = hh */
#define N6 (BATCH * 2)        /* pos   */
#define N7 (512 * 128)        /* Whpk: MFMA-fragment-packed Whh (R4) */
#define N8 (512)              /* Wx0/Wx1/bx: rank-2 fold of dec_in@Wih^T (R3) */
#define PREP_TOT (N0 + N1 + N2 + N3 + N4 + N5 + N5b + N6 + N7 + N8 + 2)

__global__ void prep_kernel(
    const float* __restrict__ W2, const float* __restrict__ Wm1,
    const float* __restrict__ Wm2, const float* __restrict__ W1,
    const float* __restrict__ Wp, const float* __restrict__ bp, const float* __restrict__ b1,
    const float* __restrict__ ch, const float* __restrict__ hh, const float* __restrict__ last_pos,
    const float* __restrict__ Wih, const float* __restrict__ Whh,
    const float* __restrict__ bih, const float* __restrict__ bhh,
    const float* __restrict__ Wse, const float* __restrict__ bse,
    unsigned short* __restrict__ W2pk, unsigned short* __restrict__ Wm1pk,
    unsigned short* __restrict__ Wm2pk, unsigned short* __restrict__ W1pk,
    float* __restrict__ Wcx, float* __restrict__ Wcy, float* __restrict__ biash,
    float* __restrict__ cbuf, float* __restrict__ hbuf, float* __restrict__ pos,
    unsigned short* __restrict__ Whpk,
    float* __restrict__ Wx0, float* __restrict__ Wx1, float* __restrict__ bx,
    float* __restrict__ loss, unsigned* __restrict__ barcnt)
{
    long idx = (long)blockIdx.x * 256 + threadIdx.x;
    if (idx < N0) {
        // W2pk[((cg*16+ksg)*64 + lane)*8 + e] = W2[col*512 + kk]
        int e = (int)(idx & 7);
        long u = idx >> 3;
        int lane = (int)(u & 63);
        int rest = (int)(u >> 6);            // 0 .. 1023
        int ksg = rest & 15, cg = rest >> 4; // cg 0..63
        int col = cg * 16 + (lane & 15);
        int kk = ksg * 32 + (lane >> 4) * 8 + e;
        W2pk[idx] = f2bf(W2[(size_t)col * PRE + kk]);
        return;
    }
    idx -= N0;
    if (idx < N1) {
        // Wm1pk[((cg*36+ksg)*64+lane)*8+e] = Wm1[col*1152 + k]
        int e = (int)(idx & 7);
        long u = idx >> 3;
        int lane = (int)(u & 63);
        long rest = u >> 6;                 // 0 .. 2303
        int ksg = (int)(rest % 36);
        int cg = (int)(rest / 36);          // 0 .. 63
        int col = cg * 16 + (lane & 15);
        int k = ksg * 32 + (lane >> 4) * 8 + e;
        Wm1pk[idx] = f2bf(Wm1[(size_t)col * AK + k]);
        return;
    }
    idx -= N1;
    if (idx < N2) {
        // Wm2pk[((cg*32+ksg)*64+lane)*8+e] = Wm2[col*1024 + k]
        int e = (int)(idx & 7);
        long u = idx >> 3;
        int lane = (int)(u & 63);
        int rest = (int)(u >> 6);           // 0 .. 255
        int ksg = rest & 31, cg = rest >> 5;
        int col = cg * 16 + (lane & 15);
        int k = ksg * 32 + (lane >> 4) * 8 + e;
        Wm2pk[idx] = f2bf(Wm2[(size_t)col * MLPD + k]);
        return;
    }
    idx -= N2;
    if (idx < N3) {
        // W1pk[(((w*4+ks)*4+nt)*4+quad)*16 + l16][e] = W1[col*192 + 64 + k]
        int e = (int)(idx & 7);
        int u = (int)(idx >> 3);
        int l16 = u & 15, quad = (u >> 4) & 3, nt = (u >> 6) & 3, ks = (u >> 8) & 3, w = u >> 10;
        int col = w * 64 + nt * 16 + l16;
        int k = ks * 32 + quad * 8 + e;
        W1pk[idx] = f2bf(W1[col * 192 + E + k]);
        return;
    }
    idx -= N3;
    if (idx < N4) {
        int p = (int)idx;
        float sx = 0.f, sy = 0.f, sb = 0.f;
#pragma unroll 8
        for (int e = 0; e < E; ++e) {
            float w = W1[p * 192 + e];
            sx += w * Wp[e * 2 + 0];
            sy += w * Wp[e * 2 + 1];
            sb += w * bp[e];
        }
        Wcx[p] = sx; Wcy[p] = sy; biash[p] = b1[p] + sb;
        return;
    }
    idx -= N4;
    if (idx < N5) { cbuf[idx] = ch[idx]; return; }
    idx -= N5;
    if (idx < N5b) { hbuf[idx] = hh[idx]; return; }
    idx -= N5b;
    if (idx < N6) { pos[idx] = last_pos[idx]; return; }
    idx -= N6;
    if (idx < N7) {
        // Whpk[(((g*8+w)*4+ks)*4+quad)*16 + l16][e] = Whh[col*128 + k]
        int e = (int)(idx & 7);
        int u = (int)(idx >> 3);
        int l16 = u & 15, quad = (u >> 4) & 3, ks = (u >> 6) & 3, w = (u >> 8) & 7, g = u >> 11;
        int col = g * 128 + w * 16 + l16;
        int k = ks * 32 + quad * 8 + e;
        Whpk[idx] = f2bf(Whh[col * H + k]);
        return;
    }
    idx -= N7;
    if (idx < N8) {
        int u = (int)idx;
        float sx = 0.f, sy = 0.f, sb = 0.f;
#pragma unroll 8
        for (int e = 0; e < E; ++e) {
            float w = Wih[u * E + e];
            sx += w * Wse[e * 2 + 0];
            sy += w * Wse[e * 2 + 1];
            sb += w * bse[e];
        }
        Wx0[u] = sx; Wx1[u] = sy; bx[u] = sb + bih[u] + bhh[u];
        return;
    }
    idx -= N8;
    if (idx == 0) { *loss = 0.0f; return; }
    if (idx == 1) { *barcnt = 0u; return; }
}

// ---------------------------------------------------------------- grid barrier
// Monotone-counter barrier. Arrive = device-scope atomicAdd (m20); spin = AGENT-scope
// atomic load; __threadfence() release/acquire gives cross-XCD visibility (G16).
// Safe: grid(256) <= co-resident capacity (512thr, 32KB LDS, launch_bounds(512,2)).
__device__ __forceinline__ void gsync(unsigned* cnt, unsigned target) {
    __syncthreads();
    if (threadIdx.x == 0) {
        __threadfence();                 // release: prior writes visible device-wide
        atomicAdd(cnt, 1u);
        while (__hip_atomic_load(cnt, __ATOMIC_RELAXED, __HIP_MEMORY_SCOPE_AGENT) < target)
            __builtin_amdgcn_s_sleep(16);
        __threadfence();                 // acquire: discard stale lines
    }
    __syncthreads();
}

// ---------------------------------------------------------------- persistent 12-step decoder (R11)
// One kernel replaces 45 launches (lstm/pool/mlp1/mlp2 x 11 + lstm). Phase bodies are
// verbatim R10 kernels; 44 grid barriers replace 44 launch gaps (~4.6us each measured
// by wall-vs-kernel-sum budget). Grid 256 x 512thr, smem = max(phase) = 32KB.
#define LROWS 16
__global__ __launch_bounds__(512, 2) void decoder_persistent(
    const float* __restrict__ last_pos_rel, const float* __restrict__ ptr_rel,
    const unsigned short* __restrict__ Whpk,
    const float* __restrict__ Wx0, const float* __restrict__ Wx1, const float* __restrict__ bx,
    const float* __restrict__ Wpos, const float* __restrict__ bpos,
    const unsigned short* __restrict__ W1pk, const float* __restrict__ biash,
    const float* __restrict__ Wcx, const float* __restrict__ Wcy,
    const unsigned short* __restrict__ W2pk, const float* __restrict__ b2,
    const unsigned short* __restrict__ Wm1pk, const float* __restrict__ bm1,
    const unsigned short* __restrict__ Wm2pk, const float* __restrict__ bm2,
    float* __restrict__ hbuf, float* __restrict__ cbuf,
    unsigned short* __restrict__ Abf, float* __restrict__ Hpartf,
    unsigned short* __restrict__ dhbf,
    float* __restrict__ pos, float* __restrict__ out, float* __restrict__ loss,
    unsigned* __restrict__ barcnt)
{
    __shared__ __align__(16) unsigned char smem[32768];
    const int blk = blockIdx.x, tid = threadIdx.x;
    const int lane = tid & 63, w = tid >> 6;          // w in 0..7
    const int quad = lane >> 4, l16 = lane & 15;
    unsigned phase = 0;

    for (int t = 0; t < SEQ; ++t) {
        // ============ phase LSTM + Hpart + pos/loss — blocks 0..31 (R2/R3/R4/R10) ============
        if (blk < 32) {
            constexpr int LDHB = 136;
            constexpr int LDHF = 129;
            unsigned short* As = (unsigned short*)smem;            // 16*136 ush
            unsigned short* hnb = As + LROWS * LDHB;               // 16*136 ush
            float* hnf = (float*)(hnb + LROWS * LDHB);             // 16*129 f32
            float* lred = hnf + LROWS * LDHF;                      // 8 f32
            const int r0 = blk * LROWS;
            const float* relin = (t == 0) ? last_pos_rel : (ptr_rel + (t - 1) * BATCH * 2);
            const float* gt = ptr_rel + t * BATCH * 2;
            float* traj = out + t * BATCH * 2;

            // ---- build A = bf16(h_in) : 16 x 128 ----
            for (int e2 = tid; e2 < LROWS * H; e2 += 512) {
                int row = e2 >> 7, k = e2 & 127;
                As[row * LDHB + k] = f2bf(hbuf[(size_t)(r0 + row) * H + k]);
            }
            __syncthreads();

            // ---- gate GEMM (K=128): wave w -> u-slice, all 4 gates ----
            f32x4 acc[4];
#pragma unroll
            for (int g4 = 0; g4 < 4; ++g4) acc[g4] = (f32x4)0.f;
#pragma unroll
            for (int ks = 0; ks < 4; ++ks) {
                bf16x8 af = *(const bf16x8*)&As[l16 * LDHB + ks * 32 + quad * 8];
#pragma unroll
                for (int gate = 0; gate < 4; ++gate) {
                    bf16x8 bf = *(const bf16x8*)&Whpk[((size_t)((gate * 8 + w) * 4 + ks) * 64 + lane) * 8];
                    acc[gate] = __builtin_amdgcn_mfma_f32_16x16x32_bf16(af, bf, acc[gate], 0, 0, 0);
                }
            }

            // ---- nonlinearity + c update ----
            {
                int u = w * 16 + l16;
                float wx0[4], wx1[4], bxv[4];
#pragma unroll
                for (int gate = 0; gate < 4; ++gate) {
                    int col = gate * 128 + u;
                    wx0[gate] = Wx0[col]; wx1[gate] = Wx1[col]; bxv[gate] = bx[col];
                }
#pragma unroll
                for (int r = 0; r < 4; ++r) {
                    int row = quad * 4 + r;
                    int b = r0 + row;
                    float rx = relin[b * 2 + 0], ry = relin[b * 2 + 1];
                    float i_ = acc[0][r] + rx * wx0[0] + ry * wx1[0] + bxv[0];
                    float f_ = acc[1][r] + rx * wx0[1] + ry * wx1[1] + bxv[1];
                    float g_ = acc[2][r] + rx * wx0[2] + ry * wx1[2] + bxv[2];
                    float o_ = acc[3][r] + rx * wx0[3] + ry * wx1[3] + bxv[3];
                    float ig = 1.0f / (1.0f + expf(-i_));
                    float fg = 1.0f / (1.0f + expf(-f_));
                    float gg = tanhf(g_);
                    float og = 1.0f / (1.0f + expf(-o_));
                    float c = fg * cbuf[(size_t)b * H + u] + ig * gg;
                    cbuf[(size_t)b * H + u] = c;
                    float h = og * tanhf(c);
                    hnb[row * LDHB + u] = f2bf(h);
                    hnf[row * LDHF + u] = h;
                    Abf[(size_t)b * AK + u] = f2bf(h);
                }
            }
            __syncthreads();

            // ---- Hpart GEMM (dead at last step) ----
            if (t < SEQ - 1) {
                f32x4 acc2[4];
#pragma unroll
                for (int nt = 0; nt < 4; ++nt) acc2[nt] = (f32x4)0.f;
#pragma unroll
                for (int ks = 0; ks < 4; ++ks) {
                    bf16x8 af = *(const bf16x8*)&hnb[l16 * LDHB + ks * 32 + quad * 8];
#pragma unroll
                    for (int nt = 0; nt < 4; ++nt) {
                        bf16x8 bfr = *(const bf16x8*)&W1pk[((size_t)((w * 4 + ks) * 4 + nt) * 64 + lane) * 8];
                        acc2[nt] = __builtin_amdgcn_mfma_f32_16x16x32_bf16(af, bfr, acc2[nt], 0, 0, 0);
                    }
                }
#pragma unroll
                for (int nt = 0; nt < 4; ++nt) {
                    int col = w * 64 + nt * 16 + l16;
                    float bv = biash[col];
#pragma unroll
                    for (int r = 0; r < 4; ++r) {
                        int row = quad * 4 + r;
                        Hpartf[(size_t)(r0 + row) * PRE + col] = acc2[nt][r] + bv;
                    }
                }
            }

            // ---- rel_pos / curr_pos / traj / loss (R10 block-reduced) ----
            {
                int row = tid >> 5, o = (tid >> 4) & 1, seg = tid & 15;
                const float* wr = Wpos + o * H + seg * 8;
                const float* hr = &hnf[row * LDHF + seg * 8];
                float acc3 = 0.f;
#pragma unroll
                for (int k = 0; k < 8; ++k) acc3 += wr[k] * hr[k];
                acc3 += __shfl_xor(acc3, 1);
                acc3 += __shfl_xor(acc3, 2);
                acc3 += __shfl_xor(acc3, 4);
                acc3 += __shfl_xor(acc3, 8);
                acc3 += bpos[o];
                int b = r0 + row;
                float d = acc3 - gt[b * 2 + o];
                if (seg == 0) {
                    float lp = pos[b * 2 + o];
                    pos[b * 2 + o] = acc3 + lp;
                    traj[b * 2 + o] = acc3;
                }
                float part = (seg == 0) ? d * d : 0.f;
                part += __shfl_xor(part, 16);
                part += __shfl_xor(part, 32);
                if (lane == 0) lred[w] = part;
                __syncthreads();
                if (tid == 0) {
                    float s = 0.f;
#pragma unroll
                    for (int i = 0; i < 8; ++i) s += lred[i];
                    atomicAdd(loss, s * (1.0f / 1024.0f));
                }
            }
        }
        if (t == SEQ - 1) break;
        ++phase; gsync(barcnt, phase * NBLK);

        // ============ phase POOL — all 256 blocks (R5/R6/R9) ============
        {
            constexpr int LDA = 72;
            unsigned short* AsP = (unsigned short*)smem;            // 128*72 ush = 18432B
            const int n_tile = blk & 1, m_tile = blk >> 1;
            const int g = m_tile >> 3, iq = m_tile & 7;
            const int n0 = n_tile * 512;
            const int brow = tid >> 2;
            const int k8 = (tid & 3) * 16;
            const int bi = iq * 4 + (brow >> 5), bj = brow & 31;
            const float rx = pos[(g * GSZ + bj) * 2 + 0] - pos[(g * GSZ + bi) * 2 + 0];
            const float ry = pos[(g * GSZ + bj) * 2 + 1] - pos[(g * GSZ + bi) * 2 + 1];
            const float* hrow = &Hpartf[(size_t)(g * GSZ + bj) * PRE];

            f32x4 acc[8][4];
#pragma unroll
            for (int mt = 0; mt < 8; ++mt)
#pragma unroll
                for (int nt = 0; nt < 4; ++nt) acc[mt][nt] = (f32x4)0.f;

            for (int k0i = 0; k0i < 8; ++k0i) {
                const int k0 = k0i * 64;
                {
                    const float4* hp = (const float4*)(hrow + k0 + k8);
                    const float4* wx = (const float4*)(Wcx + k0 + k8);
                    const float4* wy = (const float4*)(Wcy + k0 + k8);
                    bf8pack o[2];
#pragma unroll
                    for (int q = 0; q < 2; ++q) {
                        float4 ha = hp[q * 2], hb = hp[q * 2 + 1];
                        float4 xa = wx[q * 2], xb = wx[q * 2 + 1];
                        float4 ya = wy[q * 2], yb = wy[q * 2 + 1];
                        o[q].s[0] = f2bf(fmaxf(ha.x + rx * xa.x + ry * ya.x, 0.f));
                        o[q].s[1] = f2bf(fmaxf(ha.y + rx * xa.y + ry * ya.y, 0.f));
                        o[q].s[2] = f2bf(fmaxf(ha.z + rx * xa.z + ry * ya.z, 0.f));
                        o[q].s[3] = f2bf(fmaxf(ha.w + rx * xa.w + ry * ya.w, 0.f));
                        o[q].s[4] = f2bf(fmaxf(hb.x + rx * xb.x + ry * yb.x, 0.f));
                        o[q].s[5] = f2bf(fmaxf(hb.y + rx * xb.y + ry * yb.y, 0.f));
                        o[q].s[6] = f2bf(fmaxf(hb.z + rx * xb.z + ry * yb.z, 0.f));
                        o[q].s[7] = f2bf(fmaxf(hb.w + rx * xb.w + ry * yb.w, 0.f));
                    }
                    *(uint4*)&AsP[brow * LDA + k8] = o[0].v;
                    *(uint4*)&AsP[brow * LDA + k8 + 8] = o[1].v;
                }
                __syncthreads();
#pragma unroll
                for (int ks = 0; ks < 2; ++ks) {
                    bf16x8 bfr[4];
#pragma unroll
                    for (int nt = 0; nt < 4; ++nt) {
                        int cg = n_tile * 32 + w * 4 + nt;
                        int ksg = k0i * 2 + ks;
                        bfr[nt] = *(const bf16x8*)&W2pk[((size_t)(cg * 16 + ksg) * 64 + lane) * 8];
                    }
#pragma unroll
                    for (int mt = 0; mt < 8; ++mt) {
                        bf16x8 af = *(const bf16x8*)&AsP[(mt * 16 + l16) * LDA + ks * 32 + quad * 8];
#pragma unroll
                        for (int nt = 0; nt < 4; ++nt)
                            acc[mt][nt] = __builtin_amdgcn_mfma_f32_16x16x32_bf16(af, bfr[nt], acc[mt][nt], 0, 0, 0);
                    }
                }
                __syncthreads();
            }

#pragma unroll
            for (int il = 0; il < 4; ++il)
#pragma unroll
            for (int nt = 0; nt < 4; ++nt) {
                float u = -1e30f;
#pragma unroll
                for (int p = 0; p < 2; ++p)
#pragma unroll
                    for (int r = 0; r < 4; ++r) u = fmaxf(u, acc[il * 2 + p][nt][r]);
                u = fmaxf(u, __shfl_xor(u, 16));
                u = fmaxf(u, __shfl_xor(u, 32));
                if (lane < 16) {
                    int col = n0 + w * 64 + nt * 16 + l16;
                    int gu = m_tile * 4 + il;
                    Abf[(size_t)gu * AK + H + col] = f2bf(fmaxf(u + b2[col], 0.f));
                }
            }
        }
        ++phase; gsync(barcnt, phase * NBLK);

        // ============ phase MLP1 — all blocks, threads 0..255 active (R10 splitk_pk<64,32,2,2,1>) ============
        {
            const int n0 = (blk & 31) * 32, m0 = (blk >> 5) * 64;
            const bool act = tid < 256;
            unsigned short* AsM = (unsigned short*)smem;            // 2*64*64 ush = 16384B
            float* red = (float*)(smem + 16384);                    // 2*64*32 f32 = 16384B
            const int w4 = (tid >> 6) & 3;
            const int kslice = w4 >> 1, nslice = w4 & 1;
            const int gtid = tid & 127;
            const int cgbase = n0 / 16 + nslice;                    // (n0 + nslice*16)>>4

            f32x4 acc[4];
#pragma unroll
            for (int mt = 0; mt < 4; ++mt) acc[mt] = (f32x4)0.f;

            for (int k0 = 0; k0 < 576; k0 += 64) {
                int kb = kslice * 576 + k0;
                int kgbase = kb >> 5;
                if (act) {
#pragma unroll
                    for (int u = 0; u < 4; ++u) {
                        int c = u * 128 + gtid;
                        __builtin_amdgcn_global_load_lds(
                            GLB(Abf + (size_t)(m0 + (c >> 3)) * AK + kb + (c & 7) * 8),
                            LDS(&AsM[kslice * 4096 + c * 8]), 16, 0, 0);
                    }
                }
                __syncthreads();
                if (act) {
#pragma unroll
                    for (int ks = 0; ks < 2; ++ks) {
                        bf16x8 af[4];
#pragma unroll
                        for (int mt = 0; mt < 4; ++mt)
                            af[mt] = *(const bf16x8*)&AsM[kslice * 4096 + (mt * 16 + l16) * 64 + ks * 32 + quad * 8];
                        bf16x8 bfr = *(const bf16x8*)&Wm1pk[((size_t)(cgbase * 36 + kgbase + ks) * 64 + lane) * 8];
#pragma unroll
                        for (int mt = 0; mt < 4; ++mt)
                            acc[mt] = __builtin_amdgcn_mfma_f32_16x16x32_bf16(af[mt], bfr, acc[mt], 0, 0, 0);
                    }
                }
                __syncthreads();
            }

            if (act) {
#pragma unroll
                for (int mt = 0; mt < 4; ++mt)
#pragma unroll
                for (int r = 0; r < 4; ++r) {
                    int row = mt * 16 + quad * 4 + r;
                    int col = nslice * 16 + l16;
                    red[kslice * 2048 + row * 32 + col] = acc[mt][r];
                }
            }
            __syncthreads();
            if (act) {
#pragma unroll
                for (int o = 0; o < 8; ++o) {
                    int e = o * 256 + tid;
                    int row = e >> 5, col = e & 31;
                    float s = red[e] + red[2048 + e];
                    float v = fmaxf(s + bm1[n0 + col], 0.f);
                    dhbf[(size_t)(m0 + row) * MLPD + n0 + col] = f2bf(v);
                }
            }
        }
        ++phase; gsync(barcnt, phase * NBLK);

        // ============ phase MLP2 — blocks 0..127, threads 0..255 active (R10 splitk_pk<16,32,4,1,2>) ============
        if (blk < 128) {
            const int n0 = (blk & 3) * 32, m0 = (blk >> 2) * 16;
            const bool act = tid < 256;
            unsigned short* As2 = (unsigned short*)smem;            // 4*16*64 ush = 8192B
            float* red2 = (float*)(smem + 8192);                    // 4*16*32 f32 = 8192B
            const int w4 = (tid >> 6) & 3;                          // kslice
            const int gtid2 = tid & 63;
            const int cgbase = n0 >> 4;

            f32x4 acc[2];
#pragma unroll
            for (int nt = 0; nt < 2; ++nt) acc[nt] = (f32x4)0.f;

            for (int k0 = 0; k0 < 256; k0 += 64) {
                int kb = w4 * 256 + k0;
                int kgbase = kb >> 5;
                if (act) {
#pragma unroll
                    for (int u = 0; u < 2; ++u) {
                        int c = u * 64 + gtid2;
                        __builtin_amdgcn_global_load_lds(
                            GLB(dhbf + (size_t)(m0 + (c >> 3)) * MLPD + kb + (c & 7) * 8),
                            LDS(&As2[w4 * 1024 + c * 8]), 16, 0, 0);
                    }
                }
                __syncthreads();
                if (act) {
#pragma unroll
                    for (int ks = 0; ks < 2; ++ks) {
                        bf16x8 af = *(const bf16x8*)&As2[w4 * 1024 + l16 * 64 + ks * 32 + quad * 8];
#pragma unroll
                        for (int nt = 0; nt < 2; ++nt) {
                            bf16x8 bfr = *(const bf16x8*)&Wm2pk[((size_t)((cgbase + nt) * 32 + kgbase + ks) * 64 + lane) * 8];
                            acc[nt] = __builtin_amdgcn_mfma_f32_16x16x32_bf16(af, bfr, acc[nt], 0, 0, 0);
                        }
                    }
                }
                __syncthreads();
            }

            if (act) {
#pragma unroll
                for (int nt = 0; nt < 2; ++nt)
#pragma unroll
                for (int r = 0; r < 4; ++r) {
                    int row = quad * 4 + r;
                    int col = nt * 16 + l16;
                    red2[w4 * 512 + row * 32 + col] = acc[nt][r];
                }
            }
            __syncthreads();
            if (act) {
#pragma unroll
                for (int o = 0; o < 2; ++o) {
                    int e = o * 256 + tid;
                    int row = e >> 5, col = e & 31;
                    float s = red2[e] + red2[512 + e] + red2[1024 + e] + red2[1536 + e];
                    float v = fmaxf(s + bm2[n0 + col], 0.f);
                    hbuf[(size_t)(m0 + row) * H + n0 + col] = v;
                }
            }
        }
        ++phase; gsync(barcnt, phase * NBLK);
    }
}

// ---------------------------------------------------------------- launch
extern "C" void kernel_launch(void* const* d_in, const int* in_sizes, int n_in,
                              void* d_out, int out_size, void* d_ws, size_t ws_size,
                              hipStream_t stream)
{
    const float* last_pos     = (const float*)d_in[0];
    const float* last_pos_rel = (const float*)d_in[1];
    const float* hh           = (const float*)d_in[2];
    const float* ch           = (const float*)d_in[3];
    const float* ptr_rel      = (const float*)d_in[4];
    const float* Wih  = (const float*)d_in[6];
    const float* Whh  = (const float*)d_in[7];
    const float* bih  = (const float*)d_in[8];
    const float* bhh  = (const float*)d_in[9];
    const float* Wse  = (const float*)d_in[10];
    const float* bse  = (const float*)d_in[11];
    const float* Wpos = (const float*)d_in[12];
    const float* bpos = (const float*)d_in[13];
    const float* Wp   = (const float*)d_in[14];
    const float* bp   = (const float*)d_in[15];
    const float* W1   = (const float*)d_in[16];
    const float* b1   = (const float*)d_in[17];
    const float* W2   = (const float*)d_in[18];
    const float* b2   = (const float*)d_in[19];
    const float* Wm1  = (const float*)d_in[20];
    const float* bm1  = (const float*)d_in[21];
    const float* Wm2  = (const float*)d_in[22];
    const float* bm2  = (const float*)d_in[23];

    float* ws     = (float*)d_ws;
    float* hbuf   = ws;                       // 65536
    float* cbuf   = hbuf + BATCH * H;         // 65536
    float* pos    = cbuf + BATCH * H;         // 1024 (padded)
    float* Hpartf = pos + 1024;               // 262144
    float* Wcx    = Hpartf + BATCH * PRE;     // 512
    float* Wcy    = Wcx + PRE;                // 512
    float* biash  = Wcy + PRE;                // 512
    float* bx     = biash + PRE;              // 512
    float* Wx0    = bx + 512;                 // 512
    float* Wx1    = Wx0 + 512;                // 512
    unsigned short* ub    = (unsigned short*)(Wx1 + 512);
    unsigned short* Abf   = ub;                         // 512*1152
    unsigned short* dhbf  = Abf + (size_t)BATCH * AK;   // 512*1024
    unsigned short* W2pk  = dhbf + (size_t)BATCH * MLPD;
    unsigned short* Wm1pk = W2pk + (size_t)BOT * PRE;
    unsigned short* Wm2pk = Wm1pk + (size_t)MLPD * AK;
    unsigned short* W1pk  = Wm2pk + (size_t)H * MLPD;   // 512*128 (packed)
    unsigned short* Whpk  = W1pk + (size_t)PRE * H;     // 512*128 (packed)
    unsigned* barcnt      = (unsigned*)(Whpk + (size_t)512 * 128);

    float* out  = (float*)d_out;
    float* loss = out + SEQ * BATCH * 2;

    prep_kernel<<<(PREP_TOT + 255) / 256, 256, 0, stream>>>(
        W2, Wm1, Wm2, W1, Wp, bp, b1, ch, hh, last_pos, Wih, Whh, bih, bhh, Wse, bse,
        W2pk, Wm1pk, Wm2pk, W1pk, Wcx, Wcy, biash, cbuf, hbuf, pos, Whpk, Wx0, Wx1, bx,
        loss, barcnt);

    // R11: single persistent kernel for all 12 steps (was 45 launches).
    decoder_persistent<<<NBLK, 512, 0, stream>>>(
        last_pos_rel, ptr_rel, Whpk, Wx0, Wx1, bx, Wpos, bpos, W1pk, biash,
        Wcx, Wcy, W2pk, b2, Wm1pk, bm1, Wm2pk, bm2,
        hbuf, cbuf, Abf, Hpartf, dhbf, pos, out, loss, barcnt);
}

// Round 12
// 668.872 us; speedup vs baseline: 2.6992x; 2.6992x over previous
//
#include <hip/hip_runtime.h>
#include <math.h>

#define BATCH 512
#define NG 16
#define GSZ 32
#define H 128
#define E 64
#define PRE 512
#define BOT 1024
#define MLPD 1024
#define SEQ 12
#define AK 1152   // Abf row length = H + BOT

typedef __attribute__((ext_vector_type(8))) short bf16x8;
typedef __attribute__((ext_vector_type(4))) float f32x4;

union bf8pack { ushort s[8]; uint4 v; };

__device__ __forceinline__ unsigned short f2bf(float f) {
    unsigned u = __float_as_uint(f);
    u += 0x7FFF + ((u >> 16) & 1);   // round-to-nearest-even
    return (unsigned short)(u >> 16);
}

#define GLB(p) ((const __attribute__((address_space(1))) unsigned int*)(p))
#define LDS(p) ((__attribute__((address_space(3))) unsigned int*)(p))

// ---------------------------------------------------------------- one-shot prep (R10 verbatim)
#define N0 (BOT * PRE)        /* W2pk: MFMA-fragment-packed W2 (R9) */
#define N1 (MLPD * AK)        /* Wm1pk: MFMA-fragment-packed Wm1 (R10) */
#define N2 (H * MLPD)         /* Wm2pk: MFMA-fragment-packed Wm2 (R10) */
#define N3 (PRE * H)          /* W1pk: MFMA-fragment-packed W1[:,64:192] (R4) */
#define N4 (PRE)              /* wc    */
#define N5 (BATCH * H)        /* c     */
#define N5b (BATCH * H)       /* h0 = hh */
#define N6 (BATCH * 2)        /* pos   */
#define N7 (512 * 128)        /* Whpk: MFMA-fragment-packed Whh (R4) */
#define N8 (512)              /* Wx0/Wx1/bx: rank-2 fold of dec_in@Wih^T (R3) */
#define PREP_TOT (N0 + N1 + N2 + N3 + N4 + N5 + N5b + N6 + N7 + N8 + 1)

__global__ void prep_kernel(
    const float* __restrict__ W2, const float* __restrict__ Wm1,
    const float* __restrict__ Wm2, const float* __restrict__ W1,
    const float* __restrict__ Wp, const float* __restrict__ bp, const float* __restrict__ b1,
    const float* __restrict__ ch, const float* __restrict__ hh, const float* __restrict__ last_pos,
    const float* __restrict__ Wih, const float* __restrict__ Whh,
    const float* __restrict__ bih, const float* __restrict__ bhh,
    const float* __restrict__ Wse, const float* __restrict__ bse,
    unsigned short* __restrict__ W2pk, unsigned short* __restrict__ Wm1pk,
    unsigned short* __restrict__ Wm2pk, unsigned short* __restrict__ W1pk,
    float* __restrict__ Wcx, float* __restrict__ Wcy, float* __restrict__ biash,
    float* __restrict__ cbuf, float* __restrict__ hbuf, float* __restrict__ pos,
    unsigned short* __restrict__ Whpk,
    float* __restrict__ Wx0, float* __restrict__ Wx1, float* __restrict__ bx,
    float* __restrict__ loss)
{
    long idx = (long)blockIdx.x * 256 + threadIdx.x;
    if (idx < N0) {
        int e = (int)(idx & 7);
        long u = idx >> 3;
        int lane = (int)(u & 63);
        int rest = (int)(u >> 6);            // 0 .. 1023
        int ksg = rest & 15, cg = rest >> 4; // cg 0..63
        int col = cg * 16 + (lane & 15);
        int kk = ksg * 32 + (lane >> 4) * 8 + e;
        W2pk[idx] = f2bf(W2[(size_t)col * PRE + kk]);
        return;
    }
    idx -= N0;
    if (idx < N1) {
        int e = (int)(idx & 7);
        long u = idx >> 3;
        int lane = (int)(u & 63);
        long rest = u >> 6;                 // 0 .. 2303
        int ksg = (int)(rest % 36);
        int cg = (int)(rest / 36);          // 0 .. 63
        int col = cg * 16 + (lane & 15);
        int k = ksg * 32 + (lane >> 4) * 8 + e;
        Wm1pk[idx] = f2bf(Wm1[(size_t)col * AK + k]);
        return;
    }
    idx -= N1;
    if (idx < N2) {
        int e = (int)(idx & 7);
        long u = idx >> 3;
        int lane = (int)(u & 63);
        int rest = (int)(u >> 6);           // 0 .. 255
        int ksg = rest & 31, cg = rest >> 5;
        int col = cg * 16 + (lane & 15);
        int k = ksg * 32 + (lane >> 4) * 8 + e;
        Wm2pk[idx] = f2bf(Wm2[(size_t)col * MLPD + k]);
        return;
    }
    idx -= N2;
    if (idx < N3) {
        int e = (int)(idx & 7);
        int u = (int)(idx >> 3);
        int l16 = u & 15, quad = (u >> 4) & 3, nt = (u >> 6) & 3, ks = (u >> 8) & 3, w = u >> 10;
        int col = w * 64 + nt * 16 + l16;
        int k = ks * 32 + quad * 8 + e;
        W1pk[idx] = f2bf(W1[col * 192 + E + k]);
        return;
    }
    idx -= N3;
    if (idx < N4) {
        int p = (int)idx;
        float sx = 0.f, sy = 0.f, sb = 0.f;
#pragma unroll 8
        for (int e = 0; e < E; ++e) {
            float w = W1[p * 192 + e];
            sx += w * Wp[e * 2 + 0];
            sy += w * Wp[e * 2 + 1];
            sb += w * bp[e];
        }
        Wcx[p] = sx; Wcy[p] = sy; biash[p] = b1[p] + sb;
        return;
    }
    idx -= N4;
    if (idx < N5) { cbuf[idx] = ch[idx]; return; }
    idx -= N5;
    if (idx < N5b) { hbuf[idx] = hh[idx]; return; }
    idx -= N5b;
    if (idx < N6) { pos[idx] = last_pos[idx]; return; }
    idx -= N6;
    if (idx < N7) {
        int e = (int)(idx & 7);
        int u = (int)(idx >> 3);
        int l16 = u & 15, quad = (u >> 4) & 3, ks = (u >> 6) & 3, w = (u >> 8) & 7, g = u >> 11;
        int col = g * 128 + w * 16 + l16;
        int k = ks * 32 + quad * 8 + e;
        Whpk[idx] = f2bf(Whh[col * H + k]);
        return;
    }
    idx -= N7;
    if (idx < N8) {
        int u = (int)idx;
        float sx = 0.f, sy = 0.f, sb = 0.f;
#pragma unroll 8
        for (int e = 0; e < E; ++e) {
            float w = Wih[u * E + e];
            sx += w * Wse[e * 2 + 0];
            sy += w * Wse[e * 2 + 1];
            sb += w * bse[e];
        }
        Wx0[u] = sx; Wx1[u] = sy; bx[u] = sb + bih[u] + bhh[u];
        return;
    }
    idx -= N8;
    if (idx == 0) *loss = 0.0f;
}

// ---------------------------------------------------------------- fused LSTM + Hpart (R10 verbatim)
#define LROWS 16
__global__ __launch_bounds__(512) void lstm_hpart(
    int t,
    const float* __restrict__ relin, const float* __restrict__ gt,
    const unsigned short* __restrict__ Whpk,
    const float* __restrict__ Wx0, const float* __restrict__ Wx1, const float* __restrict__ bx,
    const float* __restrict__ Wpos, const float* __restrict__ bpos,
    const unsigned short* __restrict__ W1pk, const float* __restrict__ biash,
    const float* __restrict__ hbuf, float* __restrict__ cbuf,
    unsigned short* __restrict__ Abf, float* __restrict__ Hpartf,
    float* __restrict__ pos, float* __restrict__ traj, float* __restrict__ loss)
{
    constexpr int LDHB = 136;
    constexpr int LDHF = 129;
    __shared__ __align__(16) unsigned short As[LROWS * LDHB];
    __shared__ __align__(16) unsigned short hnb[LROWS * LDHB];
    __shared__ float hnf[LROWS * LDHF];
    __shared__ float lred[8];
    const int r0 = blockIdx.x * LROWS;     // global row base
    const int tid = threadIdx.x;
    const int lane = tid & 63, w = tid >> 6;          // w in 0..7
    const int quad = lane >> 4, l16 = lane & 15;

    // ---- build A = bf16(h_in) : 16 x 128 ----
    for (int idx = tid; idx < LROWS * H; idx += 512) {
        int row = idx >> 7, k = idx & 127;
        As[row * LDHB + k] = f2bf(hbuf[(size_t)(r0 + row) * H + k]);
    }
    __syncthreads();

    // ---- gate GEMM (K=128): wave w -> u-slice [w*16, w*16+16), all 4 gates ----
    f32x4 acc[4];
#pragma unroll
    for (int g4 = 0; g4 < 4; ++g4) acc[g4] = (f32x4)0.f;
#pragma unroll
    for (int ks = 0; ks < 4; ++ks) {
        bf16x8 af = *(const bf16x8*)&As[l16 * LDHB + ks * 32 + quad * 8];
#pragma unroll
        for (int gate = 0; gate < 4; ++gate) {
            bf16x8 bf = *(const bf16x8*)&Whpk[((size_t)((gate * 8 + w) * 4 + ks) * 64 + lane) * 8];
            acc[gate] = __builtin_amdgcn_mfma_f32_16x16x32_bf16(af, bf, acc[gate], 0, 0, 0);
        }
    }

    // ---- nonlinearity + c update (u = w*16 + l16, rows = quad*4+r) ----
    {
        int u = w * 16 + l16;
        float wx0[4], wx1[4], bxv[4];
#pragma unroll
        for (int gate = 0; gate < 4; ++gate) {
            int col = gate * 128 + u;
            wx0[gate] = Wx0[col]; wx1[gate] = Wx1[col]; bxv[gate] = bx[col];
        }
#pragma unroll
        for (int r = 0; r < 4; ++r) {
            int row = quad * 4 + r;
            int b = r0 + row;
            float rx = relin[b * 2 + 0], ry = relin[b * 2 + 1];
            float i_ = acc[0][r] + rx * wx0[0] + ry * wx1[0] + bxv[0];
            float f_ = acc[1][r] + rx * wx0[1] + ry * wx1[1] + bxv[1];
            float g_ = acc[2][r] + rx * wx0[2] + ry * wx1[2] + bxv[2];
            float o_ = acc[3][r] + rx * wx0[3] + ry * wx1[3] + bxv[3];
            float ig = 1.0f / (1.0f + expf(-i_));
            float fg = 1.0f / (1.0f + expf(-f_));
            float gg = tanhf(g_);
            float og = 1.0f / (1.0f + expf(-o_));
            float c = fg * cbuf[(size_t)b * H + u] + ig * gg;
            cbuf[(size_t)b * H + u] = c;
            float h = og * tanhf(c);
            hnb[row * LDHB + u] = f2bf(h);
            hnf[row * LDHF + u] = h;
            Abf[(size_t)b * AK + u] = f2bf(h);
        }
    }
    __syncthreads();

    // ---- Hpart GEMM (dead at last step): wave w -> cols [w*64, w*64+64) ----
    if (t < SEQ - 1) {
        f32x4 acc2[4];
#pragma unroll
        for (int nt = 0; nt < 4; ++nt) acc2[nt] = (f32x4)0.f;
#pragma unroll
        for (int ks = 0; ks < 4; ++ks) {
            bf16x8 af = *(const bf16x8*)&hnb[l16 * LDHB + ks * 32 + quad * 8];
#pragma unroll
            for (int nt = 0; nt < 4; ++nt) {
                bf16x8 bfr = *(const bf16x8*)&W1pk[((size_t)((w * 4 + ks) * 4 + nt) * 64 + lane) * 8];
                acc2[nt] = __builtin_amdgcn_mfma_f32_16x16x32_bf16(af, bfr, acc2[nt], 0, 0, 0);
            }
        }
#pragma unroll
        for (int nt = 0; nt < 4; ++nt) {
            int col = w * 64 + nt * 16 + l16;
            float bv = biash[col];
#pragma unroll
            for (int r = 0; r < 4; ++r) {
                int row = quad * 4 + r;
                Hpartf[(size_t)(r0 + row) * PRE + col] = acc2[nt][r] + bv;
            }
        }
    }

    // ---- rel_pos / curr_pos / traj / loss — 512 threads, 16-seg shfl reduce ----
    {
        int row = tid >> 5, o = (tid >> 4) & 1, seg = tid & 15;
        const float* wr = Wpos + o * H + seg * 8;
        const float* hr = &hnf[row * LDHF + seg * 8];
        float acc3 = 0.f;
#pragma unroll
        for (int k = 0; k < 8; ++k) acc3 += wr[k] * hr[k];
        acc3 += __shfl_xor(acc3, 1);
        acc3 += __shfl_xor(acc3, 2);
        acc3 += __shfl_xor(acc3, 4);
        acc3 += __shfl_xor(acc3, 8);
        acc3 += bpos[o];
        int b = r0 + row;
        float d = acc3 - gt[b * 2 + o];
        if (seg == 0) {
            float lp = pos[b * 2 + o];
            pos[b * 2 + o] = acc3 + lp;
            traj[b * 2 + o] = acc3;
        }
        float part = (seg == 0) ? d * d : 0.f;
        part += __shfl_xor(part, 16);
        part += __shfl_xor(part, 32);
        if (lane == 0) lred[w] = part;
        __syncthreads();
        if (tid == 0) {
            float s = 0.f;
#pragma unroll
            for (int i = 0; i < 8; ++i) s += lred[i];
            atomicAdd(loss, s * (1.0f / 1024.0f));
        }
    }
}

// ---------------------------------------------------------------- split-K bf16 MFMA GEMM, packed-B
// R10: B direct from fragment-packed global. R12: double-buffered A staging,
// ONE barrier per K-iter (sync -> MFMA(cur) -> stage(next into other buf)):
// stage loads fly under other waves' MFMA; barrier count halved.
// MODE 1: Cb = bf16(relu(acc+bias)) | MODE 2: Cf = relu(acc+bias)
template <int BM, int BN, int KW, int NW, int MODE>
__global__ __launch_bounds__(256) void gemm_splitk_pk(
    const unsigned short* __restrict__ A, int lda,
    const unsigned short* __restrict__ Bpk, int K,
    const float* __restrict__ bias,
    float* __restrict__ Cf, unsigned short* __restrict__ Cb, int ldc)
{
    constexpr int MT = BM / 16;            // A frags per wave
    constexpr int NT = BN / (16 * NW);     // B frags per wave
    constexpr int ABUF = KW * BM * 64;
    __shared__ __align__(16) unsigned short As[2 * ABUF];
    __shared__ float red[KW * BM * BN];
    int tid = threadIdx.x;
    int lane = tid & 63, w = tid >> 6;
    int kslice = w / NW, nslice = w % NW;
    int gtid = tid & (NW * 64 - 1);
    int quad = lane >> 4, l16 = lane & 15;
    int m0 = blockIdx.y * BM, n0 = blockIdx.x * BN;
    const int KC = K / KW;                 // K per slice (multiple of 64)
    const int NK = KC / 64;                // K-iterations
    const int KSGT = K >> 5;               // total 32-wide k-groups in packed B
    const int cgbase = (n0 + nslice * (BN / NW)) >> 4;

    auto STAGE = [&](int ki, int bo) {
        int kb = kslice * KC + ki * 64;
#pragma unroll
        for (int u = 0; u < BM / (8 * NW); ++u) {
            int c = u * NW * 64 + gtid;
            __builtin_amdgcn_global_load_lds(
                GLB(A + (size_t)(m0 + (c >> 3)) * lda + kb + (c & 7) * 8),
                LDS(&As[bo + kslice * BM * 64 + c * 8]), 16, 0, 0);
        }
    };

    f32x4 acc[MT][NT];
#pragma unroll
    for (int mt = 0; mt < MT; ++mt)
#pragma unroll
        for (int nt = 0; nt < NT; ++nt) acc[mt][nt] = (f32x4)0.f;

    STAGE(0, 0);
    for (int ki = 0; ki < NK; ++ki) {
        int bo = (ki & 1) * ABUF;
        int kgbase = (kslice * KC + ki * 64) >> 5;
        __syncthreads();                    // drains stage(ki) (implicit vmcnt(0))
#pragma unroll
        for (int ks = 0; ks < 2; ++ks) {
            bf16x8 af[MT], bfr[NT];
#pragma unroll
            for (int mt = 0; mt < MT; ++mt)
                af[mt] = *(const bf16x8*)&As[bo + kslice * BM * 64 + (mt * 16 + l16) * 64 + ks * 32 + quad * 8];
#pragma unroll
            for (int nt = 0; nt < NT; ++nt)
                bfr[nt] = *(const bf16x8*)&Bpk[((size_t)((cgbase + nt) * KSGT + kgbase + ks) * 64 + lane) * 8];
#pragma unroll
            for (int mt = 0; mt < MT; ++mt)
#pragma unroll
                for (int nt = 0; nt < NT; ++nt)
                    acc[mt][nt] = __builtin_amdgcn_mfma_f32_16x16x32_bf16(af[mt], bfr[nt], acc[mt][nt], 0, 0, 0);
        }
        if (ki + 1 < NK) STAGE(ki + 1, ((ki + 1) & 1) * ABUF);
    }

    // ---- partials -> LDS ----
#pragma unroll
    for (int mt = 0; mt < MT; ++mt)
#pragma unroll
    for (int nt = 0; nt < NT; ++nt) {
#pragma unroll
        for (int r = 0; r < 4; ++r) {
            int row = mt * 16 + quad * 4 + r;
            int col = nslice * (BN / NW) + nt * 16 + l16;
            red[kslice * BM * BN + row * BN + col] = acc[mt][nt][r];
        }
    }
    __syncthreads();

    // ---- reduce KW partials + bias + relu + store ----
#pragma unroll
    for (int o = 0; o < BM * BN / 256; ++o) {
        int e = o * 256 + tid;
        int row = e / BN, col = e % BN;
        float s = 0.f;
#pragma unroll
        for (int k = 0; k < KW; ++k) s += red[k * BM * BN + e];
        float v = fmaxf(s + bias[n0 + col], 0.f);
        if (MODE == 1) Cb[(size_t)(m0 + row) * ldc + n0 + col] = f2bf(v);
        else           Cf[(size_t)(m0 + row) * ldc + n0 + col] = v;
    }
}

// ---------------------------------------------------------------- fused x1-build + pool GEMM + max_j
// R9: B direct from fragment-packed W2pk (no Bs LDS, no bank conflicts).
// R12: double-buffered A-build, ONE barrier per K-step (was 2): sync -> MFMA(cur)
// -> build(next into other buf). Build's Hpart loads overlap other waves' MFMA.
__global__ __launch_bounds__(512) void pool_fused(
    const float* __restrict__ Hpartf, const float* __restrict__ pos,
    const float* __restrict__ Wcx, const float* __restrict__ Wcy,
    const unsigned short* __restrict__ W2pk,
    const float* __restrict__ b2, unsigned short* __restrict__ Abf)
{
    constexpr int LDA = 72;    // pad: row stride 144B -> 2-way bank aliasing (free, m136)
    constexpr int ASZ = 128 * LDA;
    __shared__ __align__(16) unsigned short As[2 * ASZ];   // 36 KB double-buffered
    const int tid = threadIdx.x;
    const int lane = tid & 63, w = tid >> 6;       // 8 waves
    const int quad = lane >> 4, l16 = lane & 15;
    const int n_tile = blockIdx.x, m_tile = blockIdx.y;
    const int g = m_tile >> 3, iq = m_tile & 7;
    const int n0 = n_tile * 512;

    // per-thread build coords (loop-invariant): thread -> (row, 16-col slab)
    const int brow = tid >> 2;                 // 0..127
    const int k8 = (tid & 3) * 16;             // col base within K-step
    const int bi = iq * 4 + (brow >> 5), bj = brow & 31;
    const float rx = pos[(g * GSZ + bj) * 2 + 0] - pos[(g * GSZ + bi) * 2 + 0];
    const float ry = pos[(g * GSZ + bj) * 2 + 1] - pos[(g * GSZ + bi) * 2 + 1];
    const float* hrow = &Hpartf[(size_t)(g * GSZ + bj) * PRE];

    auto BUILD = [&](int k0i, unsigned short* dst) {
        const int k0 = k0i * 64;
        const float4* hp = (const float4*)(hrow + k0 + k8);
        const float4* wx = (const float4*)(Wcx + k0 + k8);
        const float4* wy = (const float4*)(Wcy + k0 + k8);
        bf8pack o[2];
#pragma unroll
        for (int q = 0; q < 2; ++q) {
            float4 ha = hp[q * 2], hb = hp[q * 2 + 1];
            float4 xa = wx[q * 2], xb = wx[q * 2 + 1];
            float4 ya = wy[q * 2], yb = wy[q * 2 + 1];
            o[q].s[0] = f2bf(fmaxf(ha.x + rx * xa.x + ry * ya.x, 0.f));
            o[q].s[1] = f2bf(fmaxf(ha.y + rx * xa.y + ry * ya.y, 0.f));
            o[q].s[2] = f2bf(fmaxf(ha.z + rx * xa.z + ry * ya.z, 0.f));
            o[q].s[3] = f2bf(fmaxf(ha.w + rx * xa.w + ry * ya.w, 0.f));
            o[q].s[4] = f2bf(fmaxf(hb.x + rx * xb.x + ry * yb.x, 0.f));
            o[q].s[5] = f2bf(fmaxf(hb.y + rx * xb.y + ry * yb.y, 0.f));
            o[q].s[6] = f2bf(fmaxf(hb.z + rx * xb.z + ry * yb.z, 0.f));
            o[q].s[7] = f2bf(fmaxf(hb.w + rx * xb.w + ry * yb.w, 0.f));
        }
        *(uint4*)&dst[brow * LDA + k8] = o[0].v;
        *(uint4*)&dst[brow * LDA + k8 + 8] = o[1].v;
    };

    f32x4 acc[8][4];
#pragma unroll
    for (int mt = 0; mt < 8; ++mt)
#pragma unroll
        for (int nt = 0; nt < 4; ++nt) acc[mt][nt] = (f32x4)0.f;

    BUILD(0, As);
    for (int k0i = 0; k0i < 8; ++k0i) {
        unsigned short* cur = As + (k0i & 1) * ASZ;
        __syncthreads();                   // build(k0i) visible; mfma(k0i-1) done before buf reuse
#pragma unroll
        for (int ks = 0; ks < 2; ++ks) {
            bf16x8 bfr[4];
#pragma unroll
            for (int nt = 0; nt < 4; ++nt) {
                int cg = n_tile * 32 + w * 4 + nt;
                int ksg = k0i * 2 + ks;
                bfr[nt] = *(const bf16x8*)&W2pk[((size_t)(cg * 16 + ksg) * 64 + lane) * 8];
            }
#pragma unroll
            for (int mt = 0; mt < 8; ++mt) {
                bf16x8 af = *(const bf16x8*)&cur[(mt * 16 + l16) * LDA + ks * 32 + quad * 8];
#pragma unroll
                for (int nt = 0; nt < 4; ++nt)
                    acc[mt][nt] = __builtin_amdgcn_mfma_f32_16x16x32_bf16(af, bfr[nt], acc[mt][nt], 0, 0, 0);
            }
        }
        if (k0i < 7) BUILD(k0i + 1, As + ((k0i + 1) & 1) * ASZ);
    }

    // ---- max over j: rows il*32..il*32+31 live in acc[2il..2il+1] x quad lanes ----
#pragma unroll
    for (int il = 0; il < 4; ++il)
#pragma unroll
    for (int nt = 0; nt < 4; ++nt) {
        float u = -1e30f;
#pragma unroll
        for (int p = 0; p < 2; ++p)
#pragma unroll
            for (int r = 0; r < 4; ++r) u = fmaxf(u, acc[il * 2 + p][nt][r]);
        u = fmaxf(u, __shfl_xor(u, 16));
        u = fmaxf(u, __shfl_xor(u, 32));
        if (lane < 16) {
            int col = n0 + w * 64 + nt * 16 + l16;
            int gu = m_tile * 4 + il;
            Abf[(size_t)gu * AK + H + col] = f2bf(fmaxf(u + b2[col], 0.f));
        }
    }
}

// ---------------------------------------------------------------- launch
extern "C" void kernel_launch(void* const* d_in, const int* in_sizes, int n_in,
                              void* d_out, int out_size, void* d_ws, size_t ws_size,
                              hipStream_t stream)
{
    const float* last_pos     = (const float*)d_in[0];
    const float* last_pos_rel = (const float*)d_in[1];
    const float* hh           = (const float*)d_in[2];
    const float* ch           = (const float*)d_in[3];
    const float* ptr_rel      = (const float*)d_in[4];
    const float* Wih  = (const float*)d_in[6];
    const float* Whh  = (const float*)d_in[7];
    const float* bih  = (const float*)d_in[8];
    const float* bhh  = (const float*)d_in[9];
    const float* Wse  = (const float*)d_in[10];
    const float* bse  = (const float*)d_in[11];
    const float* Wpos = (const float*)d_in[12];
    const float* bpos = (const float*)d_in[13];
    const float* Wp   = (const float*)d_in[14];
    const float* bp   = (const float*)d_in[15];
    const float* W1   = (const float*)d_in[16];
    const float* b1   = (const float*)d_in[17];
    const float* W2   = (const float*)d_in[18];
    const float* b2   = (const float*)d_in[19];
    const float* Wm1  = (const float*)d_in[20];
    const float* bm1  = (const float*)d_in[21];
    const float* Wm2  = (const float*)d_in[22];
    const float* bm2  = (const float*)d_in[23];

    float* ws     = (float*)d_ws;
    float* hbuf   = ws;                       // 65536
    float* cbuf   = hbuf + BATCH * H;         // 65536
    float* pos    = cbuf + BATCH * H;         // 1024 (padded)
    float* Hpartf = pos + 1024;               // 262144
    float* Wcx    = Hpartf + BATCH * PRE;     // 512
    float* Wcy    = Wcx + PRE;                // 512
    float* biash  = Wcy + PRE;                // 512
    float* bx     = biash + PRE;              // 512
    float* Wx0    = bx + 512;                 // 512
    float* Wx1    = Wx0 + 512;                // 512
    unsigned short* ub    = (unsigned short*)(Wx1 + 512);
    unsigned short* Abf   = ub;                         // 512*1152
    unsigned short* dhbf  = Abf + (size_t)BATCH * AK;   // 512*1024
    unsigned short* W2pk  = dhbf + (size_t)BATCH * MLPD;
    unsigned short* Wm1pk = W2pk + (size_t)BOT * PRE;
    unsigned short* Wm2pk = Wm1pk + (size_t)MLPD * AK;
    unsigned short* W1pk  = Wm2pk + (size_t)H * MLPD;   // 512*128 (packed)
    unsigned short* Whpk  = W1pk + (size_t)PRE * H;     // 512*128 (packed)

    float* out  = (float*)d_out;
    float* loss = out + SEQ * BATCH * 2;

    prep_kernel<<<(PREP_TOT + 255) / 256, 256, 0, stream>>>(
        W2, Wm1, Wm2, W1, Wp, bp, b1, ch, hh, last_pos, Wih, Whh, bih, bhh, Wse, bse,
        W2pk, Wm1pk, Wm2pk, W1pk, Wcx, Wcy, biash, cbuf, hbuf, pos, Whpk, Wx0, Wx1, bx, loss);

    for (int t = 0; t < SEQ; t++) {
        const float* relin = (t == 0) ? last_pos_rel : (ptr_rel + (t - 1) * BATCH * 2);
        const float* gt = ptr_rel + t * BATCH * 2;
        // fused LSTM gates (MFMA, K=128, packed-B) + Hpart (MFMA, packed-B) + rel_pos/loss
        lstm_hpart<<<BATCH / LROWS, 512, 0, stream>>>(t, relin, gt, Whpk, Wx0, Wx1, bx,
                                                      Wpos, bpos, W1pk, biash, hbuf, cbuf,
                                                      Abf, Hpartf, pos,
                                                      out + t * BATCH * 2, loss);
        if (t == SEQ - 1) break;   // h after last step is dead
        // fused x1-build + pool GEMM + max_j — R12: dbuf A, 1 barrier/K-step
        pool_fused<<<dim3(2, 128), 512, 0, stream>>>(Hpartf, pos, Wcx, Wcy, W2pk, b2, Abf);
        // dh = bf16(relu([h|pool] @ Wm1^T + bm1)) — 2-way split-K, packed-B, dbuf A (R12)
        gemm_splitk_pk<64, 32, 2, 2, 1><<<dim3(MLPD / 32, BATCH / 64), 256, 0, stream>>>(
            Abf, AK, Wm1pk, AK, bm1, nullptr, dhbf, MLPD);
        // h = relu(dh @ Wm2^T + bm2) -> fp32 hbuf — 4-way split-K, packed-B, dbuf A (R12)
        gemm_splitk_pk<16, 32, 4, 1, 2><<<dim3(H / 32, BATCH / 16), 256, 0, stream>>>(
            dhbf, MLPD, Wm2pk, MLPD, bm2, hbuf, nullptr, H);
    }
}

// Round 13
// 665.104 us; speedup vs baseline: 2.7145x; 1.0057x over previous
//
#include <hip/hip_runtime.h>
#include <math.h>

#define BATCH 512
#define NG 16
#define GSZ 32
#define H 128
#define E 64
#define PRE 512
#define BOT 1024
#define MLPD 1024
#define SEQ 12
#define AK 1152   // Abf row length = H + BOT

typedef __attribute__((ext_vector_type(8))) short bf16x8;
typedef __attribute__((ext_vector_type(4))) float f32x4;

union bf8pack { ushort s[8]; uint4 v; };

__device__ __forceinline__ unsigned short f2bf(float f) {
    unsigned u = __float_as_uint(f);
    u += 0x7FFF + ((u >> 16) & 1);   // round-to-nearest-even
    return (unsigned short)(u >> 16);
}

__device__ __forceinline__ uint4 pack8(const float* s) {
    float4 a = *(const float4*)s, b = *(const float4*)(s + 4);
    bf8pack o;
    o.s[0] = f2bf(a.x); o.s[1] = f2bf(a.y); o.s[2] = f2bf(a.z); o.s[3] = f2bf(a.w);
    o.s[4] = f2bf(b.x); o.s[5] = f2bf(b.y); o.s[6] = f2bf(b.z); o.s[7] = f2bf(b.w);
    return o.v;
}

#define GLB(p) ((const __attribute__((address_space(1))) unsigned int*)(p))
#define LDS(p) ((__attribute__((address_space(3))) unsigned int*)(p))

// ---------------------------------------------------------------- one-shot prep
// R13: 8-wide vectorized — 8 consecutive packed elems share the index decode and
// a contiguous source row: 1 decode + 2 float4 loads + 1 uint4 store per thread.
#define U0 ((BOT * PRE) / 8)     /* W2pk   */
#define U1 ((MLPD * AK) / 8)     /* Wm1pk  */
#define U2 ((H * MLPD) / 8)      /* Wm2pk  */
#define U3 ((PRE * H) / 8)       /* W1pk   */
#define U4 (PRE)                 /* wc (scalar) */
#define U5 ((BATCH * H) / 4)     /* cbuf float4 copy */
#define U5b ((BATCH * H) / 8)    /* Ahpk pack of hh (R13) */
#define U6 (BATCH * 2)           /* pos (scalar) */
#define U7 ((512 * 128) / 8)     /* Whpk   */
#define U8 (512)                 /* Wx0/Wx1/bx */
#define PREP_TOT (U0 + U1 + U2 + U3 + U4 + U5 + U5b + U6 + U7 + U8 + 1)

__global__ void prep_kernel(
    const float* __restrict__ W2, const float* __restrict__ Wm1,
    const float* __restrict__ Wm2, const float* __restrict__ W1,
    const float* __restrict__ Wp, const float* __restrict__ bp, const float* __restrict__ b1,
    const float* __restrict__ ch, const float* __restrict__ hh, const float* __restrict__ last_pos,
    const float* __restrict__ Wih, const float* __restrict__ Whh,
    const float* __restrict__ bih, const float* __restrict__ bhh,
    const float* __restrict__ Wse, const float* __restrict__ bse,
    unsigned short* __restrict__ W2pk, unsigned short* __restrict__ Wm1pk,
    unsigned short* __restrict__ Wm2pk, unsigned short* __restrict__ W1pk,
    float* __restrict__ Wcx, float* __restrict__ Wcy, float* __restrict__ biash,
    float* __restrict__ cbuf, unsigned short* __restrict__ Ahpk, float* __restrict__ pos,
    unsigned short* __restrict__ Whpk,
    float* __restrict__ Wx0, float* __restrict__ Wx1, float* __restrict__ bx,
    float* __restrict__ loss)
{
    long idx = (long)blockIdx.x * 256 + threadIdx.x;
    if (idx < U0) {
        // W2pk unit u: lane=u&63, rest=u>>6: ksg=rest&15, cg=rest>>4
        int u = (int)idx;
        int lane = u & 63, rest = u >> 6;
        int ksg = rest & 15, cg = rest >> 4;
        int col = cg * 16 + (lane & 15);
        int kk = ksg * 32 + (lane >> 4) * 8;
        *(uint4*)&W2pk[(size_t)u * 8] = pack8(&W2[(size_t)col * PRE + kk]);
        return;
    }
    idx -= U0;
    if (idx < U1) {
        // Wm1pk unit u: lane=u&63, rest=u>>6: ksg=rest%36, cg=rest/36
        int u = (int)idx;
        int lane = u & 63, rest = u >> 6;
        int ksg = rest % 36, cg = rest / 36;
        int col = cg * 16 + (lane & 15);
        int k = ksg * 32 + (lane >> 4) * 8;
        *(uint4*)&Wm1pk[(size_t)u * 8] = pack8(&Wm1[(size_t)col * AK + k]);
        return;
    }
    idx -= U1;
    if (idx < U2) {
        // Wm2pk unit u: lane=u&63, rest=u>>6: ksg=rest&31, cg=rest>>5
        int u = (int)idx;
        int lane = u & 63, rest = u >> 6;
        int ksg = rest & 31, cg = rest >> 5;
        int col = cg * 16 + (lane & 15);
        int k = ksg * 32 + (lane >> 4) * 8;
        *(uint4*)&Wm2pk[(size_t)u * 8] = pack8(&Wm2[(size_t)col * MLPD + k]);
        return;
    }
    idx -= U2;
    if (idx < U3) {
        // W1pk unit u: l16=u&15, quad=(u>>4)&3, nt=(u>>6)&3, ks=(u>>8)&3, w=u>>10
        int u = (int)idx;
        int l16 = u & 15, quad = (u >> 4) & 3, nt = (u >> 6) & 3, ks = (u >> 8) & 3, w = u >> 10;
        int col = w * 64 + nt * 16 + l16;
        int k = ks * 32 + quad * 8;
        *(uint4*)&W1pk[(size_t)u * 8] = pack8(&W1[col * 192 + E + k]);
        return;
    }
    idx -= U3;
    if (idx < U4) {
        int p = (int)idx;
        float sx = 0.f, sy = 0.f, sb = 0.f;
#pragma unroll 8
        for (int e = 0; e < E; ++e) {
            float w = W1[p * 192 + e];
            sx += w * Wp[e * 2 + 0];
            sy += w * Wp[e * 2 + 1];
            sb += w * bp[e];
        }
        Wcx[p] = sx; Wcy[p] = sy; biash[p] = b1[p] + sb;
        return;
    }
    idx -= U4;
    if (idx < U5) { ((float4*)cbuf)[idx] = ((const float4*)ch)[idx]; return; }
    idx -= U5;
    if (idx < U5b) {
        // Ahpk pack of hh: unit u: lane=u&63, rest=u>>6: ks=rest&3, rowtile=rest>>2
        int u = (int)idx;
        int lane = u & 63, rest = u >> 6;
        int ks = rest & 3, rowtile = rest >> 2;
        int row = rowtile * 16 + (lane & 15);
        int k = ks * 32 + (lane >> 4) * 8;
        *(uint4*)&Ahpk[(size_t)u * 8] = pack8(&hh[(size_t)row * H + k]);
        return;
    }
    idx -= U5b;
    if (idx < U6) { pos[idx] = last_pos[idx]; return; }
    idx -= U6;
    if (idx < U7) {
        // Whpk unit u: l16=u&15, quad=(u>>4)&3, ks=(u>>6)&3, w=(u>>8)&7, g=u>>11
        int u = (int)idx;
        int l16 = u & 15, quad = (u >> 4) & 3, ks = (u >> 6) & 3, w = (u >> 8) & 7, g = u >> 11;
        int col = g * 128 + w * 16 + l16;
        int k = ks * 32 + quad * 8;
        *(uint4*)&Whpk[(size_t)u * 8] = pack8(&Whh[(size_t)col * H + k]);
        return;
    }
    idx -= U7;
    if (idx < U8) {
        int u = (int)idx;
        float sx = 0.f, sy = 0.f, sb = 0.f;
#pragma unroll 8
        for (int e = 0; e < E; ++e) {
            float w = Wih[u * E + e];
            sx += w * Wse[e * 2 + 0];
            sy += w * Wse[e * 2 + 1];
            sb += w * bse[e];
        }
        Wx0[u] = sx; Wx1[u] = sy; bx[u] = sb + bih[u] + bhh[u];
        return;
    }
    idx -= U8;
    if (idx == 0) *loss = 0.0f;
}

// ---------------------------------------------------------------- fused LSTM + Hpart
// R13: gate-A comes pre-packed from Ahpk (written by mlp2 / prep) — the A-build
// loop, its LDS buffer, and the first barrier are gone; fragment loads are
// base + lane*16B from a 128KB L2-resident buffer.
#define LROWS 16
__global__ __launch_bounds__(512) void lstm_hpart(
    int t,
    const float* __restrict__ relin, const float* __restrict__ gt,
    const unsigned short* __restrict__ Whpk,
    const float* __restrict__ Wx0, const float* __restrict__ Wx1, const float* __restrict__ bx,
    const float* __restrict__ Wpos, const float* __restrict__ bpos,
    const unsigned short* __restrict__ W1pk, const float* __restrict__ biash,
    const unsigned short* __restrict__ Ahpk, float* __restrict__ cbuf,
    unsigned short* __restrict__ Abf, float* __restrict__ Hpartf,
    float* __restrict__ pos, float* __restrict__ traj, float* __restrict__ loss)
{
    constexpr int LDHB = 136;
    constexpr int LDHF = 129;
    __shared__ __align__(16) unsigned short hnb[LROWS * LDHB];
    __shared__ float hnf[LROWS * LDHF];
    __shared__ float lred[8];
    const int blk = blockIdx.x;
    const int r0 = blk * LROWS;            // global row base (rowtile = blk)
    const int tid = threadIdx.x;
    const int lane = tid & 63, w = tid >> 6;          // w in 0..7
    const int quad = lane >> 4, l16 = lane & 15;

    // ---- gate GEMM (K=128): A fragments direct from packed Ahpk ----
    f32x4 acc[4];
#pragma unroll
    for (int g4 = 0; g4 < 4; ++g4) acc[g4] = (f32x4)0.f;
#pragma unroll
    for (int ks = 0; ks < 4; ++ks) {
        bf16x8 af = *(const bf16x8*)&Ahpk[((size_t)(blk * 4 + ks) * 64 + lane) * 8];
#pragma unroll
        for (int gate = 0; gate < 4; ++gate) {
            bf16x8 bf = *(const bf16x8*)&Whpk[((size_t)((gate * 8 + w) * 4 + ks) * 64 + lane) * 8];
            acc[gate] = __builtin_amdgcn_mfma_f32_16x16x32_bf16(af, bf, acc[gate], 0, 0, 0);
        }
    }

    // ---- nonlinearity + c update (u = w*16 + l16, rows = quad*4+r) ----
    {
        int u = w * 16 + l16;
        float wx0[4], wx1[4], bxv[4];
#pragma unroll
        for (int gate = 0; gate < 4; ++gate) {
            int col = gate * 128 + u;
            wx0[gate] = Wx0[col]; wx1[gate] = Wx1[col]; bxv[gate] = bx[col];
        }
#pragma unroll
        for (int r = 0; r < 4; ++r) {
            int row = quad * 4 + r;
            int b = r0 + row;
            float rx = relin[b * 2 + 0], ry = relin[b * 2 + 1];
            float i_ = acc[0][r] + rx * wx0[0] + ry * wx1[0] + bxv[0];
            float f_ = acc[1][r] + rx * wx0[1] + ry * wx1[1] + bxv[1];
            float g_ = acc[2][r] + rx * wx0[2] + ry * wx1[2] + bxv[2];
            float o_ = acc[3][r] + rx * wx0[3] + ry * wx1[3] + bxv[3];
            float ig = 1.0f / (1.0f + expf(-i_));
            float fg = 1.0f / (1.0f + expf(-f_));
            float gg = tanhf(g_);
            float og = 1.0f / (1.0f + expf(-o_));
            float c = fg * cbuf[(size_t)b * H + u] + ig * gg;
            cbuf[(size_t)b * H + u] = c;
            float h = og * tanhf(c);
            hnb[row * LDHB + u] = f2bf(h);
            hnf[row * LDHF + u] = h;
            Abf[(size_t)b * AK + u] = f2bf(h);
        }
    }
    __syncthreads();

    // ---- Hpart GEMM (dead at last step): wave w -> cols [w*64, w*64+64) ----
    if (t < SEQ - 1) {
        f32x4 acc2[4];
#pragma unroll
        for (int nt = 0; nt < 4; ++nt) acc2[nt] = (f32x4)0.f;
#pragma unroll
        for (int ks = 0; ks < 4; ++ks) {
            bf16x8 af = *(const bf16x8*)&hnb[l16 * LDHB + ks * 32 + quad * 8];
#pragma unroll
            for (int nt = 0; nt < 4; ++nt) {
                bf16x8 bfr = *(const bf16x8*)&W1pk[((size_t)((w * 4 + ks) * 4 + nt) * 64 + lane) * 8];
                acc2[nt] = __builtin_amdgcn_mfma_f32_16x16x32_bf16(af, bfr, acc2[nt], 0, 0, 0);
            }
        }
#pragma unroll
        for (int nt = 0; nt < 4; ++nt) {
            int col = w * 64 + nt * 16 + l16;
            float bv = biash[col];
#pragma unroll
            for (int r = 0; r < 4; ++r) {
                int row = quad * 4 + r;
                Hpartf[(size_t)(r0 + row) * PRE + col] = acc2[nt][r] + bv;
            }
        }
    }

    // ---- rel_pos / curr_pos / traj / loss — 512 threads, 16-seg shfl reduce ----
    {
        int row = tid >> 5, o = (tid >> 4) & 1, seg = tid & 15;
        const float* wr = Wpos + o * H + seg * 8;
        const float* hr = &hnf[row * LDHF + seg * 8];
        float acc3 = 0.f;
#pragma unroll
        for (int k = 0; k < 8; ++k) acc3 += wr[k] * hr[k];
        acc3 += __shfl_xor(acc3, 1);
        acc3 += __shfl_xor(acc3, 2);
        acc3 += __shfl_xor(acc3, 4);
        acc3 += __shfl_xor(acc3, 8);
        acc3 += bpos[o];
        int b = r0 + row;
        float d = acc3 - gt[b * 2 + o];
        if (seg == 0) {
            float lp = pos[b * 2 + o];
            pos[b * 2 + o] = acc3 + lp;
            traj[b * 2 + o] = acc3;
        }
        float part = (seg == 0) ? d * d : 0.f;
        part += __shfl_xor(part, 16);
        part += __shfl_xor(part, 32);
        if (lane == 0) lred[w] = part;
        __syncthreads();
        if (tid == 0) {
            float s = 0.f;
#pragma unroll
            for (int i = 0; i < 8; ++i) s += lred[i];
            atomicAdd(loss, s * (1.0f / 1024.0f));
        }
    }
}

// ---------------------------------------------------------------- split-K bf16 MFMA GEMM, packed-B
// R12: dbuf A staging, one barrier/K-iter. R13: MODE 3 writes relu output as
// MFMA-fragment-packed bf16 (Ahpk) — same float value, f2bf at the same point.
// MODE 1: Cb = bf16(relu(acc+bias)) row-major | MODE 2: Cf row-major f32 | MODE 3: Cb packed
template <int BM, int BN, int KW, int NW, int MODE>
__global__ __launch_bounds__(256) void gemm_splitk_pk(
    const unsigned short* __restrict__ A, int lda,
    const unsigned short* __restrict__ Bpk, int K,
    const float* __restrict__ bias,
    float* __restrict__ Cf, unsigned short* __restrict__ Cb, int ldc)
{
    constexpr int MT = BM / 16;            // A frags per wave
    constexpr int NT = BN / (16 * NW);     // B frags per wave
    constexpr int ABUF = KW * BM * 64;
    __shared__ __align__(16) unsigned short As[2 * ABUF];
    __shared__ float red[KW * BM * BN];
    int tid = threadIdx.x;
    int lane = tid & 63, w = tid >> 6;
    int kslice = w / NW, nslice = w % NW;
    int gtid = tid & (NW * 64 - 1);
    int quad = lane >> 4, l16 = lane & 15;
    int m0 = blockIdx.y * BM, n0 = blockIdx.x * BN;
    const int KC = K / KW;                 // K per slice (multiple of 64)
    const int NK = KC / 64;                // K-iterations
    const int KSGT = K >> 5;               // total 32-wide k-groups in packed B
    const int cgbase = (n0 + nslice * (BN / NW)) >> 4;

    auto STAGE = [&](int ki, int bo) {
        int kb = kslice * KC + ki * 64;
#pragma unroll
        for (int u = 0; u < BM / (8 * NW); ++u) {
            int c = u * NW * 64 + gtid;
            __builtin_amdgcn_global_load_lds(
                GLB(A + (size_t)(m0 + (c >> 3)) * lda + kb + (c & 7) * 8),
                LDS(&As[bo + kslice * BM * 64 + c * 8]), 16, 0, 0);
        }
    };

    f32x4 acc[MT][NT];
#pragma unroll
    for (int mt = 0; mt < MT; ++mt)
#pragma unroll
        for (int nt = 0; nt < NT; ++nt) acc[mt][nt] = (f32x4)0.f;

    STAGE(0, 0);
    for (int ki = 0; ki < NK; ++ki) {
        int bo = (ki & 1) * ABUF;
        int kgbase = (kslice * KC + ki * 64) >> 5;
        __syncthreads();                    // drains stage(ki) (implicit vmcnt(0))
#pragma unroll
        for (int ks = 0; ks < 2; ++ks) {
            bf16x8 af[MT], bfr[NT];
#pragma unroll
            for (int mt = 0; mt < MT; ++mt)
                af[mt] = *(const bf16x8*)&As[bo + kslice * BM * 64 + (mt * 16 + l16) * 64 + ks * 32 + quad * 8];
#pragma unroll
            for (int nt = 0; nt < NT; ++nt)
                bfr[nt] = *(const bf16x8*)&Bpk[((size_t)((cgbase + nt) * KSGT + kgbase + ks) * 64 + lane) * 8];
#pragma unroll
            for (int mt = 0; mt < MT; ++mt)
#pragma unroll
                for (int nt = 0; nt < NT; ++nt)
                    acc[mt][nt] = __builtin_amdgcn_mfma_f32_16x16x32_bf16(af[mt], bfr[nt], acc[mt][nt], 0, 0, 0);
        }
        if (ki + 1 < NK) STAGE(ki + 1, ((ki + 1) & 1) * ABUF);
    }

    // ---- partials -> LDS ----
#pragma unroll
    for (int mt = 0; mt < MT; ++mt)
#pragma unroll
    for (int nt = 0; nt < NT; ++nt) {
#pragma unroll
        for (int r = 0; r < 4; ++r) {
            int row = mt * 16 + quad * 4 + r;
            int col = nslice * (BN / NW) + nt * 16 + l16;
            red[kslice * BM * BN + row * BN + col] = acc[mt][nt][r];
        }
    }
    __syncthreads();

    // ---- reduce KW partials + bias + relu + store ----
#pragma unroll
    for (int o = 0; o < BM * BN / 256; ++o) {
        int e = o * 256 + tid;
        int row = e / BN, col = e % BN;
        float s = 0.f;
#pragma unroll
        for (int k = 0; k < KW; ++k) s += red[k * BM * BN + e];
        float v = fmaxf(s + bias[n0 + col], 0.f);
        if (MODE == 1) {
            Cb[(size_t)(m0 + row) * ldc + n0 + col] = f2bf(v);
        } else if (MODE == 2) {
            Cf[(size_t)(m0 + row) * ldc + n0 + col] = v;
        } else {
            // MODE 3: packed gate-A write (Ahpk layout)
            int gr = m0 + row, gc = n0 + col;
            int rowtile = gr >> 4, l16p = gr & 15;
            int ksv = gc >> 5, quadp = (gc >> 3) & 3, ep = gc & 7;
            int lanep = quadp * 16 + l16p;
            Cb[((size_t)(rowtile * 4 + ksv) * 64 + lanep) * 8 + ep] = f2bf(v);
        }
    }
}

// ---------------------------------------------------------------- fused x1-build + pool GEMM + max_j
// R9: B direct from fragment-packed W2pk. R12: dbuf A-build, 1 barrier/K-step.
// R13: s_setprio(1) around the MFMA cluster (T5; build/MFMA role-split exists).
__global__ __launch_bounds__(512) void pool_fused(
    const float* __restrict__ Hpartf, const float* __restrict__ pos,
    const float* __restrict__ Wcx, const float* __restrict__ Wcy,
    const unsigned short* __restrict__ W2pk,
    const float* __restrict__ b2, unsigned short* __restrict__ Abf)
{
    constexpr int LDA = 72;    // pad: row stride 144B -> 2-way bank aliasing (free, m136)
    constexpr int ASZ = 128 * LDA;
    __shared__ __align__(16) unsigned short As[2 * ASZ];   // 36 KB double-buffered
    const int tid = threadIdx.x;
    const int lane = tid & 63, w = tid >> 6;       // 8 waves
    const int quad = lane >> 4, l16 = lane & 15;
    const int n_tile = blockIdx.x, m_tile = blockIdx.y;
    const int g = m_tile >> 3, iq = m_tile & 7;
    const int n0 = n_tile * 512;

    // per-thread build coords (loop-invariant): thread -> (row, 16-col slab)
    const int brow = tid >> 2;                 // 0..127
    const int k8 = (tid & 3) * 16;             // col base within K-step
    const int bi = iq * 4 + (brow >> 5), bj = brow & 31;
    const float rx = pos[(g * GSZ + bj) * 2 + 0] - pos[(g * GSZ + bi) * 2 + 0];
    const float ry = pos[(g * GSZ + bj) * 2 + 1] - pos[(g * GSZ + bi) * 2 + 1];
    const float* hrow = &Hpartf[(size_t)(g * GSZ + bj) * PRE];

    auto BUILD = [&](int k0i, unsigned short* dst) {
        const int k0 = k0i * 64;
        const float4* hp = (const float4*)(hrow + k0 + k8);
        const float4* wx = (const float4*)(Wcx + k0 + k8);
        const float4* wy = (const float4*)(Wcy + k0 + k8);
        bf8pack o[2];
#pragma unroll
        for (int q = 0; q < 2; ++q) {
            float4 ha = hp[q * 2], hb = hp[q * 2 + 1];
            float4 xa = wx[q * 2], xb = wx[q * 2 + 1];
            float4 ya = wy[q * 2], yb = wy[q * 2 + 1];
            o[q].s[0] = f2bf(fmaxf(ha.x + rx * xa.x + ry * ya.x, 0.f));
            o[q].s[1] = f2bf(fmaxf(ha.y + rx * xa.y + ry * ya.y, 0.f));
            o[q].s[2] = f2bf(fmaxf(ha.z + rx * xa.z + ry * ya.z, 0.f));
            o[q].s[3] = f2bf(fmaxf(ha.w + rx * xa.w + ry * ya.w, 0.f));
            o[q].s[4] = f2bf(fmaxf(hb.x + rx * xb.x + ry * yb.x, 0.f));
            o[q].s[5] = f2bf(fmaxf(hb.y + rx * xb.y + ry * yb.y, 0.f));
            o[q].s[6] = f2bf(fmaxf(hb.z + rx * xb.z + ry * yb.z, 0.f));
            o[q].s[7] = f2bf(fmaxf(hb.w + rx * xb.w + ry * yb.w, 0.f));
        }
        *(uint4*)&dst[brow * LDA + k8] = o[0].v;
        *(uint4*)&dst[brow * LDA + k8 + 8] = o[1].v;
    };

    f32x4 acc[8][4];
#pragma unroll
    for (int mt = 0; mt < 8; ++mt)
#pragma unroll
        for (int nt = 0; nt < 4; ++nt) acc[mt][nt] = (f32x4)0.f;

    BUILD(0, As);
    for (int k0i = 0; k0i < 8; ++k0i) {
        unsigned short* cur = As + (k0i & 1) * ASZ;
        __syncthreads();                   // build(k0i) visible; mfma(k0i-1) done before buf reuse
        __builtin_amdgcn_s_setprio(1);
#pragma unroll
        for (int ks = 0; ks < 2; ++ks) {
            bf16x8 bfr[4];
#pragma unroll
            for (int nt = 0; nt < 4; ++nt) {
                int cg = n_tile * 32 + w * 4 + nt;
                int ksg = k0i * 2 + ks;
                bfr[nt] = *(const bf16x8*)&W2pk[((size_t)(cg * 16 + ksg) * 64 + lane) * 8];
            }
#pragma unroll
            for (int mt = 0; mt < 8; ++mt) {
                bf16x8 af = *(const bf16x8*)&cur[(mt * 16 + l16) * LDA + ks * 32 + quad * 8];
#pragma unroll
                for (int nt = 0; nt < 4; ++nt)
                    acc[mt][nt] = __builtin_amdgcn_mfma_f32_16x16x32_bf16(af, bfr[nt], acc[mt][nt], 0, 0, 0);
            }
        }
        __builtin_amdgcn_s_setprio(0);
        if (k0i < 7) BUILD(k0i + 1, As + ((k0i + 1) & 1) * ASZ);
    }

    // ---- max over j: rows il*32..il*32+31 live in acc[2il..2il+1] x quad lanes ----
#pragma unroll
    for (int il = 0; il < 4; ++il)
#pragma unroll
    for (int nt = 0; nt < 4; ++nt) {
        float u = -1e30f;
#pragma unroll
        for (int p = 0; p < 2; ++p)
#pragma unroll
            for (int r = 0; r < 4; ++r) u = fmaxf(u, acc[il * 2 + p][nt][r]);
        u = fmaxf(u, __shfl_xor(u, 16));
        u = fmaxf(u, __shfl_xor(u, 32));
        if (lane < 16) {
            int col = n0 + w * 64 + nt * 16 + l16;
            int gu = m_tile * 4 + il;
            Abf[(size_t)gu * AK + H + col] = f2bf(fmaxf(u + b2[col], 0.f));
        }
    }
}

// ---------------------------------------------------------------- launch
extern "C" void kernel_launch(void* const* d_in, const int* in_sizes, int n_in,
                              void* d_out, int out_size, void* d_ws, size_t ws_size,
                              hipStream_t stream)
{
    const float* last_pos     = (const float*)d_in[0];
    const float* last_pos_rel = (const float*)d_in[1];
    const float* hh           = (const float*)d_in[2];
    const float* ch           = (const float*)d_in[3];
    const float* ptr_rel      = (const float*)d_in[4];
    const float* Wih  = (const float*)d_in[6];
    const float* Whh  = (const float*)d_in[7];
    const float* bih  = (const float*)d_in[8];
    const float* bhh  = (const float*)d_in[9];
    const float* Wse  = (const float*)d_in[10];
    const float* bse  = (const float*)d_in[11];
    const float* Wpos = (const float*)d_in[12];
    const float* bpos = (const float*)d_in[13];
    const float* Wp   = (const float*)d_in[14];
    const float* bp   = (const float*)d_in[15];
    const float* W1   = (const float*)d_in[16];
    const float* b1   = (const float*)d_in[17];
    const float* W2   = (const float*)d_in[18];
    const float* b2   = (const float*)d_in[19];
    const float* Wm1  = (const float*)d_in[20];
    const float* bm1  = (const float*)d_in[21];
    const float* Wm2  = (const float*)d_in[22];
    const float* bm2  = (const float*)d_in[23];

    float* ws     = (float*)d_ws;
    unsigned short* Ahpk = (unsigned short*)ws;  // 64K ushort = 128KB (reuses old hbuf slot, 256KB)
    float* cbuf   = ws + BATCH * H;           // 65536
    float* pos    = cbuf + BATCH * H;         // 1024 (padded)
    float* Hpartf = pos + 1024;               // 262144
    float* Wcx    = Hpartf + BATCH * PRE;     // 512
    float* Wcy    = Wcx + PRE;                // 512
    float* biash  = Wcy + PRE;                // 512
    float* bx     = biash + PRE;              // 512
    float* Wx0    = bx + 512;                 // 512
    float* Wx1    = Wx0 + 512;                // 512
    unsigned short* ub    = (unsigned short*)(Wx1 + 512);
    unsigned short* Abf   = ub;                         // 512*1152
    unsigned short* dhbf  = Abf + (size_t)BATCH * AK;   // 512*1024
    unsigned short* W2pk  = dhbf + (size_t)BATCH * MLPD;
    unsigned short* Wm1pk = W2pk + (size_t)BOT * PRE;
    unsigned short* Wm2pk = Wm1pk + (size_t)MLPD * AK;
    unsigned short* W1pk  = Wm2pk + (size_t)H * MLPD;   // 512*128 (packed)
    unsigned short* Whpk  = W1pk + (size_t)PRE * H;     // 512*128 (packed)

    float* out  = (float*)d_out;
    float* loss = out + SEQ * BATCH * 2;

    prep_kernel<<<(PREP_TOT + 255) / 256, 256, 0, stream>>>(
        W2, Wm1, Wm2, W1, Wp, bp, b1, ch, hh, last_pos, Wih, Whh, bih, bhh, Wse, bse,
        W2pk, Wm1pk, Wm2pk, W1pk, Wcx, Wcy, biash, cbuf, Ahpk, pos, Whpk, Wx0, Wx1, bx, loss);

    for (int t = 0; t < SEQ; t++) {
        const float* relin = (t == 0) ? last_pos_rel : (ptr_rel + (t - 1) * BATCH * 2);
        const float* gt = ptr_rel + t * BATCH * 2;
        // fused LSTM gates (packed-A direct from Ahpk, R13) + Hpart + rel_pos/loss
        lstm_hpart<<<BATCH / LROWS, 512, 0, stream>>>(t, relin, gt, Whpk, Wx0, Wx1, bx,
                                                      Wpos, bpos, W1pk, biash, Ahpk, cbuf,
                                                      Abf, Hpartf, pos,
                                                      out + t * BATCH * 2, loss);
        if (t == SEQ - 1) break;   // h after last step is dead
        // fused x1-build + pool GEMM + max_j — dbuf A, 1 barrier/K-step, setprio (R13)
        pool_fused<<<dim3(2, 128), 512, 0, stream>>>(Hpartf, pos, Wcx, Wcy, W2pk, b2, Abf);
        // dh = bf16(relu([h|pool] @ Wm1^T + bm1)) — 2-way split-K, packed-B, dbuf A
        gemm_splitk_pk<64, 32, 2, 2, 1><<<dim3(MLPD / 32, BATCH / 64), 256, 0, stream>>>(
            Abf, AK, Wm1pk, AK, bm1, nullptr, dhbf, MLPD);
        // h = relu(dh @ Wm2^T + bm2) -> packed Ahpk for next-step gate GEMM (R13, MODE 3)
        gemm_splitk_pk<16, 32, 4, 1, 3><<<dim3(H / 32, BATCH / 16), 256, 0, stream>>>(
            dhbf, MLPD, Wm2pk, MLPD, bm2, nullptr, Ahpk, H);
    }
}

// Round 14
// 644.960 us; speedup vs baseline: 2.7993x; 1.0312x over previous
//
#include <hip/hip_runtime.h>
#include <math.h>

#define BATCH 512
#define NG 16
#define GSZ 32
#define H 128
#define E 64
#define PRE 512
#define BOT 1024
#define MLPD 1024
#define SEQ 12
#define AK 1152   // Abf row length = H + BOT

typedef __attribute__((ext_vector_type(8))) short bf16x8;
typedef __attribute__((ext_vector_type(4))) float f32x4;

union bf8pack { ushort s[8]; uint4 v; };

__device__ __forceinline__ unsigned short f2bf(float f) {
    unsigned u = __float_as_uint(f);
    u += 0x7FFF + ((u >> 16) & 1);   // round-to-nearest-even
    return (unsigned short)(u >> 16);
}

__device__ __forceinline__ uint4 pack8(const float* s) {
    float4 a = *(const float4*)s, b = *(const float4*)(s + 4);
    bf8pack o;
    o.s[0] = f2bf(a.x); o.s[1] = f2bf(a.y); o.s[2] = f2bf(a.z); o.s[3] = f2bf(a.w);
    o.s[4] = f2bf(b.x); o.s[5] = f2bf(b.y); o.s[6] = f2bf(b.z); o.s[7] = f2bf(b.w);
    return o.v;
}

#define GLB(p) ((const __attribute__((address_space(1))) unsigned int*)(p))
#define LDS(p) ((__attribute__((address_space(3))) unsigned int*)(p))

// ---------------------------------------------------------------- one-shot prep (R13, 8-wide)
#define U0 ((BOT * PRE) / 8)     /* W2pk   */
#define U1 ((MLPD * AK) / 8)     /* Wm1pk  */
#define U2 ((H * MLPD) / 8)      /* Wm2pk  */
#define U3 ((PRE * H) / 8)       /* W1pk   */
#define U4 (PRE)                 /* wc (scalar) */
#define U5 ((BATCH * H) / 4)     /* cbuf float4 copy */
#define U5b ((BATCH * H) / 8)    /* Ahpk pack of hh (t=0 gate-A) */
#define U6 (BATCH * 2)           /* pos (scalar) */
#define U7 ((512 * 128) / 8)     /* Whpk   */
#define U8 (512)                 /* Wx0/Wx1/bx */
#define PREP_TOT (U0 + U1 + U2 + U3 + U4 + U5 + U5b + U6 + U7 + U8 + 1)

__global__ void prep_kernel(
    const float* __restrict__ W2, const float* __restrict__ Wm1,
    const float* __restrict__ Wm2, const float* __restrict__ W1,
    const float* __restrict__ Wp, const float* __restrict__ bp, const float* __restrict__ b1,
    const float* __restrict__ ch, const float* __restrict__ hh, const float* __restrict__ last_pos,
    const float* __restrict__ Wih, const float* __restrict__ Whh,
    const float* __restrict__ bih, const float* __restrict__ bhh,
    const float* __restrict__ Wse, const float* __restrict__ bse,
    unsigned short* __restrict__ W2pk, unsigned short* __restrict__ Wm1pk,
    unsigned short* __restrict__ Wm2pk, unsigned short* __restrict__ W1pk,
    float* __restrict__ Wcx, float* __restrict__ Wcy, float* __restrict__ biash,
    float* __restrict__ cbuf, unsigned short* __restrict__ Ahpk, float* __restrict__ pos,
    unsigned short* __restrict__ Whpk,
    float* __restrict__ Wx0, float* __restrict__ Wx1, float* __restrict__ bx,
    float* __restrict__ loss)
{
    long idx = (long)blockIdx.x * 256 + threadIdx.x;
    if (idx < U0) {
        int u = (int)idx;
        int lane = u & 63, rest = u >> 6;
        int ksg = rest & 15, cg = rest >> 4;
        int col = cg * 16 + (lane & 15);
        int kk = ksg * 32 + (lane >> 4) * 8;
        *(uint4*)&W2pk[(size_t)u * 8] = pack8(&W2[(size_t)col * PRE + kk]);
        return;
    }
    idx -= U0;
    if (idx < U1) {
        int u = (int)idx;
        int lane = u & 63, rest = u >> 6;
        int ksg = rest % 36, cg = rest / 36;
        int col = cg * 16 + (lane & 15);
        int k = ksg * 32 + (lane >> 4) * 8;
        *(uint4*)&Wm1pk[(size_t)u * 8] = pack8(&Wm1[(size_t)col * AK + k]);
        return;
    }
    idx -= U1;
    if (idx < U2) {
        int u = (int)idx;
        int lane = u & 63, rest = u >> 6;
        int ksg = rest & 31, cg = rest >> 5;
        int col = cg * 16 + (lane & 15);
        int k = ksg * 32 + (lane >> 4) * 8;
        *(uint4*)&Wm2pk[(size_t)u * 8] = pack8(&Wm2[(size_t)col * MLPD + k]);
        return;
    }
    idx -= U2;
    if (idx < U3) {
        int u = (int)idx;
        int l16 = u & 15, quad = (u >> 4) & 3, nt = (u >> 6) & 3, ks = (u >> 8) & 3, w = u >> 10;
        int col = w * 64 + nt * 16 + l16;
        int k = ks * 32 + quad * 8;
        *(uint4*)&W1pk[(size_t)u * 8] = pack8(&W1[col * 192 + E + k]);
        return;
    }
    idx -= U3;
    if (idx < U4) {
        int p = (int)idx;
        float sx = 0.f, sy = 0.f, sb = 0.f;
#pragma unroll 8
        for (int e = 0; e < E; ++e) {
            float w = W1[p * 192 + e];
            sx += w * Wp[e * 2 + 0];
            sy += w * Wp[e * 2 + 1];
            sb += w * bp[e];
        }
        Wcx[p] = sx; Wcy[p] = sy; biash[p] = b1[p] + sb;
        return;
    }
    idx -= U4;
    if (idx < U5) { ((float4*)cbuf)[idx] = ((const float4*)ch)[idx]; return; }
    idx -= U5;
    if (idx < U5b) {
        int u = (int)idx;
        int lane = u & 63, rest = u >> 6;
        int ks = rest & 3, rowtile = rest >> 2;
        int row = rowtile * 16 + (lane & 15);
        int k = ks * 32 + (lane >> 4) * 8;
        *(uint4*)&Ahpk[(size_t)u * 8] = pack8(&hh[(size_t)row * H + k]);
        return;
    }
    idx -= U5b;
    if (idx < U6) { pos[idx] = last_pos[idx]; return; }
    idx -= U6;
    if (idx < U7) {
        int u = (int)idx;
        int l16 = u & 15, quad = (u >> 4) & 3, ks = (u >> 6) & 3, w = (u >> 8) & 7, g = u >> 11;
        int col = g * 128 + w * 16 + l16;
        int k = ks * 32 + quad * 8;
        *(uint4*)&Whpk[(size_t)u * 8] = pack8(&Whh[(size_t)col * H + k]);
        return;
    }
    idx -= U7;
    if (idx < U8) {
        int u = (int)idx;
        float sx = 0.f, sy = 0.f, sb = 0.f;
#pragma unroll 8
        for (int e = 0; e < E; ++e) {
            float w = Wih[u * E + e];
            sx += w * Wse[e * 2 + 0];
            sy += w * Wse[e * 2 + 1];
            sb += w * bse[e];
        }
        Wx0[u] = sx; Wx1[u] = sy; bx[u] = sb + bih[u] + bhh[u];
        return;
    }
    idx -= U8;
    if (idx == 0) *loss = 0.0f;
}

// ---------------------------------------------------------------- lstm body (shared by t=0 kernel and fused kernel)
// hmb: LDS 16x136 bf16 gate-A (h input); writes h_new, Hpart, pos/traj/loss.
__device__ __forceinline__ void lstm_body(
    int s, int r0, int tid, int lane, int w, int quad, int l16,
    unsigned short* hmb /*gate-A in LDS*/, unsigned short* hnb, float* hnf, float* lred,
    const float* relin, const float* gt,
    const unsigned short* Whpk,
    const float* Wx0, const float* Wx1, const float* bx,
    const float* Wpos, const float* bpos,
    const unsigned short* W1pk, const float* biash,
    float* cbuf, unsigned short* Abf, float* Hpartf,
    float* pos, float* traj, float* loss)
{
    constexpr int LDHB = 136;
    constexpr int LDHF = 129;

    // ---- gate GEMM (K=128): A from LDS hmb ----
    f32x4 acc[4];
#pragma unroll
    for (int g4 = 0; g4 < 4; ++g4) acc[g4] = (f32x4)0.f;
#pragma unroll
    for (int ks = 0; ks < 4; ++ks) {
        bf16x8 af = *(const bf16x8*)&hmb[l16 * LDHB + ks * 32 + quad * 8];
#pragma unroll
        for (int gate = 0; gate < 4; ++gate) {
            bf16x8 bf = *(const bf16x8*)&Whpk[((size_t)((gate * 8 + w) * 4 + ks) * 64 + lane) * 8];
            acc[gate] = __builtin_amdgcn_mfma_f32_16x16x32_bf16(af, bf, acc[gate], 0, 0, 0);
        }
    }

    // ---- nonlinearity + c update ----
    {
        int u = w * 16 + l16;
        float wx0[4], wx1[4], bxv[4];
#pragma unroll
        for (int gate = 0; gate < 4; ++gate) {
            int col = gate * 128 + u;
            wx0[gate] = Wx0[col]; wx1[gate] = Wx1[col]; bxv[gate] = bx[col];
        }
#pragma unroll
        for (int r = 0; r < 4; ++r) {
            int row = quad * 4 + r;
            int b = r0 + row;
            float rx = relin[b * 2 + 0], ry = relin[b * 2 + 1];
            float i_ = acc[0][r] + rx * wx0[0] + ry * wx1[0] + bxv[0];
            float f_ = acc[1][r] + rx * wx0[1] + ry * wx1[1] + bxv[1];
            float g_ = acc[2][r] + rx * wx0[2] + ry * wx1[2] + bxv[2];
            float o_ = acc[3][r] + rx * wx0[3] + ry * wx1[3] + bxv[3];
            float ig = 1.0f / (1.0f + expf(-i_));
            float fg = 1.0f / (1.0f + expf(-f_));
            float gg = tanhf(g_);
            float og = 1.0f / (1.0f + expf(-o_));
            float c = fg * cbuf[(size_t)b * H + u] + ig * gg;
            cbuf[(size_t)b * H + u] = c;
            float h = og * tanhf(c);
            hnb[row * LDHB + u] = f2bf(h);
            hnf[row * LDHF + u] = h;
            Abf[(size_t)b * AK + u] = f2bf(h);
        }
    }
    __syncthreads();

    // ---- Hpart GEMM (dead at last step) ----
    if (s < SEQ - 1) {
        f32x4 acc2[4];
#pragma unroll
        for (int nt = 0; nt < 4; ++nt) acc2[nt] = (f32x4)0.f;
#pragma unroll
        for (int ks = 0; ks < 4; ++ks) {
            bf16x8 af = *(const bf16x8*)&hnb[l16 * LDHB + ks * 32 + quad * 8];
#pragma unroll
            for (int nt = 0; nt < 4; ++nt) {
                bf16x8 bfr = *(const bf16x8*)&W1pk[((size_t)((w * 4 + ks) * 4 + nt) * 64 + lane) * 8];
                acc2[nt] = __builtin_amdgcn_mfma_f32_16x16x32_bf16(af, bfr, acc2[nt], 0, 0, 0);
            }
        }
#pragma unroll
        for (int nt = 0; nt < 4; ++nt) {
            int col = w * 64 + nt * 16 + l16;
            float bv = biash[col];
#pragma unroll
            for (int r = 0; r < 4; ++r) {
                int row = quad * 4 + r;
                Hpartf[(size_t)(r0 + row) * PRE + col] = acc2[nt][r] + bv;
            }
        }
    }

    // ---- rel_pos / curr_pos / traj / loss ----
    {
        int row = tid >> 5, o = (tid >> 4) & 1, seg = tid & 15;
        const float* wr = Wpos + o * H + seg * 8;
        const float* hr = &hnf[row * LDHF + seg * 8];
        float acc3 = 0.f;
#pragma unroll
        for (int k = 0; k < 8; ++k) acc3 += wr[k] * hr[k];
        acc3 += __shfl_xor(acc3, 1);
        acc3 += __shfl_xor(acc3, 2);
        acc3 += __shfl_xor(acc3, 4);
        acc3 += __shfl_xor(acc3, 8);
        acc3 += bpos[o];
        int b = r0 + row;
        float d = acc3 - gt[b * 2 + o];
        if (seg == 0) {
            float lp = pos[b * 2 + o];
            pos[b * 2 + o] = acc3 + lp;
            traj[b * 2 + o] = acc3;
        }
        float part = (seg == 0) ? d * d : 0.f;
        part += __shfl_xor(part, 16);
        part += __shfl_xor(part, 32);
        if (lane == 0) lred[w] = part;
        __syncthreads();
        if (tid == 0) {
            float s2 = 0.f;
#pragma unroll
            for (int i = 0; i < 8; ++i) s2 += lred[i];
            atomicAdd(loss, s2 * (1.0f / 1024.0f));
        }
    }
}

// ---------------------------------------------------------------- standalone LSTM (t=0 only; gate-A from prep-packed Ahpk)
#define LROWS 16
__global__ __launch_bounds__(512) void lstm_hpart(
    const float* __restrict__ relin, const float* __restrict__ gt,
    const unsigned short* __restrict__ Whpk,
    const float* __restrict__ Wx0, const float* __restrict__ Wx1, const float* __restrict__ bx,
    const float* __restrict__ Wpos, const float* __restrict__ bpos,
    const unsigned short* __restrict__ W1pk, const float* __restrict__ biash,
    const unsigned short* __restrict__ Ahpk, float* __restrict__ cbuf,
    unsigned short* __restrict__ Abf, float* __restrict__ Hpartf,
    float* __restrict__ pos, float* __restrict__ traj, float* __restrict__ loss)
{
    constexpr int LDHB = 136;
    constexpr int LDHF = 129;
    __shared__ __align__(16) unsigned short hmb[LROWS * LDHB];
    __shared__ __align__(16) unsigned short hnb[LROWS * LDHB];
    __shared__ float hnf[LROWS * LDHF];
    __shared__ float lred[8];
    const int blk = blockIdx.x, tid = threadIdx.x;
    const int lane = tid & 63, w = tid >> 6;
    const int quad = lane >> 4, l16 = lane & 15;

    // unpack gate-A into LDS (packed Ahpk -> hmb rows)
    for (int e2 = tid; e2 < LROWS * H / 8; e2 += 512) {
        // unit: lane2=e2&63, ks=e2>>6 within this rowtile(blk)
        int lane2 = e2 & 63, ks = e2 >> 6;
        int row = lane2 & 15, k = ks * 32 + (lane2 >> 4) * 8;
        *(uint4*)&hmb[row * LDHB + k] = *(const uint4*)&Ahpk[((size_t)(blk * 4 + ks) * 64 + lane2) * 8];
    }
    __syncthreads();

    lstm_body(0, blk * LROWS, tid, lane, w, quad, l16, hmb, hnb, hnf, lred,
              relin, gt, Whpk, Wx0, Wx1, bx, Wpos, bpos, W1pk, biash,
              cbuf, Abf, Hpartf, pos, traj, loss);
}

// ---------------------------------------------------------------- fused MLP2 + LSTM(s) (R14)
// 32 blocks x 512 thr. Phase A: h = relu(dh@Wm2^T+bm2), wave w -> cols w*16..;
// both operands fragment-packed in global (dhpk from mlp1 MODE 3, Wm2pk) -> zero
// staging, h lands in LDS. Phase B: full lstm_body for step s with gate-A = h.
// Removes 11 dispatches (4.5us gap each, R10 budget model) + Ahpk round-trip.
__global__ __launch_bounds__(512) void mlp2_lstm(
    int s,
    const unsigned short* __restrict__ dhpk,
    const unsigned short* __restrict__ Wm2pk, const float* __restrict__ bm2,
    const float* __restrict__ relin, const float* __restrict__ gt,
    const unsigned short* __restrict__ Whpk,
    const float* __restrict__ Wx0, const float* __restrict__ Wx1, const float* __restrict__ bx,
    const float* __restrict__ Wpos, const float* __restrict__ bpos,
    const unsigned short* __restrict__ W1pk, const float* __restrict__ biash,
    float* __restrict__ cbuf,
    unsigned short* __restrict__ Abf, float* __restrict__ Hpartf,
    float* __restrict__ pos, float* __restrict__ traj, float* __restrict__ loss)
{
    constexpr int LDHB = 136;
    constexpr int LDHF = 129;
    __shared__ __align__(16) unsigned short hmb[LROWS * LDHB];
    __shared__ __align__(16) unsigned short hnb[LROWS * LDHB];
    __shared__ float hnf[LROWS * LDHF];
    __shared__ float lred[8];
    const int blk = blockIdx.x, tid = threadIdx.x;
    const int lane = tid & 63, w = tid >> 6;
    const int quad = lane >> 4, l16 = lane & 15;

    // ---- phase A: mlp2 — wave w owns cols w*16..w*16+16, K=1024 ----
    f32x4 acc0 = (f32x4)0.f;
#pragma unroll 8
    for (int ki = 0; ki < 32; ++ki) {
        bf16x8 af = *(const bf16x8*)&dhpk[((size_t)(blk * 32 + ki) * 64 + lane) * 8];
        bf16x8 bf = *(const bf16x8*)&Wm2pk[((size_t)(w * 32 + ki) * 64 + lane) * 8];
        acc0 = __builtin_amdgcn_mfma_f32_16x16x32_bf16(af, bf, acc0, 0, 0, 0);
    }
    {
        int u = w * 16 + l16;
        float bv = bm2[u];
#pragma unroll
        for (int r = 0; r < 4; ++r)
            hmb[(quad * 4 + r) * LDHB + u] = f2bf(fmaxf(acc0[r] + bv, 0.f));
    }
    __syncthreads();

    // ---- phase B: lstm step s, gate-A = hmb ----
    lstm_body(s, blk * LROWS, tid, lane, w, quad, l16, hmb, hnb, hnf, lred,
              relin, gt, Whpk, Wx0, Wx1, bx, Wpos, bpos, W1pk, biash,
              cbuf, Abf, Hpartf, pos, traj, loss);
}

// ---------------------------------------------------------------- split-K bf16 MFMA GEMM, packed-B (R12 dbuf)
// MODE 1: Cb row-major bf16 | MODE 2: Cf row-major f32 | MODE 3: Cb fragment-packed
// (kgroups = ldc/32; used by mlp1 -> dhpk for the fused mlp2 consumer, R14)
template <int BM, int BN, int KW, int NW, int MODE>
__global__ __launch_bounds__(256) void gemm_splitk_pk(
    const unsigned short* __restrict__ A, int lda,
    const unsigned short* __restrict__ Bpk, int K,
    const float* __restrict__ bias,
    float* __restrict__ Cf, unsigned short* __restrict__ Cb, int ldc)
{
    constexpr int MT = BM / 16;
    constexpr int NT = BN / (16 * NW);
    constexpr int ABUF = KW * BM * 64;
    __shared__ __align__(16) unsigned short As[2 * ABUF];
    __shared__ float red[KW * BM * BN];
    int tid = threadIdx.x;
    int lane = tid & 63, w = tid >> 6;
    int kslice = w / NW, nslice = w % NW;
    int gtid = tid & (NW * 64 - 1);
    int quad = lane >> 4, l16 = lane & 15;
    int m0 = blockIdx.y * BM, n0 = blockIdx.x * BN;
    const int KC = K / KW;
    const int NK = KC / 64;
    const int KSGT = K >> 5;
    const int cgbase = (n0 + nslice * (BN / NW)) >> 4;

    auto STAGE = [&](int ki, int bo) {
        int kb = kslice * KC + ki * 64;
#pragma unroll
        for (int u = 0; u < BM / (8 * NW); ++u) {
            int c = u * NW * 64 + gtid;
            __builtin_amdgcn_global_load_lds(
                GLB(A + (size_t)(m0 + (c >> 3)) * lda + kb + (c & 7) * 8),
                LDS(&As[bo + kslice * BM * 64 + c * 8]), 16, 0, 0);
        }
    };

    f32x4 acc[MT][NT];
#pragma unroll
    for (int mt = 0; mt < MT; ++mt)
#pragma unroll
        for (int nt = 0; nt < NT; ++nt) acc[mt][nt] = (f32x4)0.f;

    STAGE(0, 0);
    for (int ki = 0; ki < NK; ++ki) {
        int bo = (ki & 1) * ABUF;
        int kgbase = (kslice * KC + ki * 64) >> 5;
        __syncthreads();
#pragma unroll
        for (int ks = 0; ks < 2; ++ks) {
            bf16x8 af[MT], bfr[NT];
#pragma unroll
            for (int mt = 0; mt < MT; ++mt)
                af[mt] = *(const bf16x8*)&As[bo + kslice * BM * 64 + (mt * 16 + l16) * 64 + ks * 32 + quad * 8];
#pragma unroll
            for (int nt = 0; nt < NT; ++nt)
                bfr[nt] = *(const bf16x8*)&Bpk[((size_t)((cgbase + nt) * KSGT + kgbase + ks) * 64 + lane) * 8];
#pragma unroll
            for (int mt = 0; mt < MT; ++mt)
#pragma unroll
                for (int nt = 0; nt < NT; ++nt)
                    acc[mt][nt] = __builtin_amdgcn_mfma_f32_16x16x32_bf16(af[mt], bfr[nt], acc[mt][nt], 0, 0, 0);
        }
        if (ki + 1 < NK) STAGE(ki + 1, ((ki + 1) & 1) * ABUF);
    }

#pragma unroll
    for (int mt = 0; mt < MT; ++mt)
#pragma unroll
    for (int nt = 0; nt < NT; ++nt) {
#pragma unroll
        for (int r = 0; r < 4; ++r) {
            int row = mt * 16 + quad * 4 + r;
            int col = nslice * (BN / NW) + nt * 16 + l16;
            red[kslice * BM * BN + row * BN + col] = acc[mt][nt][r];
        }
    }
    __syncthreads();

#pragma unroll
    for (int o = 0; o < BM * BN / 256; ++o) {
        int e = o * 256 + tid;
        int row = e / BN, col = e % BN;
        float s = 0.f;
#pragma unroll
        for (int k = 0; k < KW; ++k) s += red[k * BM * BN + e];
        float v = fmaxf(s + bias[n0 + col], 0.f);
        if (MODE == 1) {
            Cb[(size_t)(m0 + row) * ldc + n0 + col] = f2bf(v);
        } else if (MODE == 2) {
            Cf[(size_t)(m0 + row) * ldc + n0 + col] = v;
        } else {
            // MODE 3: fragment-packed write; kgroups = ldc/32
            int gr = m0 + row, gc = n0 + col;
            int rowtile = gr >> 4, l16p = gr & 15;
            int ksv = gc >> 5, quadp = (gc >> 3) & 3, ep = gc & 7;
            int lanep = quadp * 16 + l16p;
            Cb[((size_t)(rowtile * (ldc >> 5) + ksv) * 64 + lanep) * 8 + ep] = f2bf(v);
        }
    }
}

// ---------------------------------------------------------------- fused x1-build + pool GEMM + max_j (R12/R13)
__global__ __launch_bounds__(512) void pool_fused(
    const float* __restrict__ Hpartf, const float* __restrict__ pos,
    const float* __restrict__ Wcx, const float* __restrict__ Wcy,
    const unsigned short* __restrict__ W2pk,
    const float* __restrict__ b2, unsigned short* __restrict__ Abf)
{
    constexpr int LDA = 72;
    constexpr int ASZ = 128 * LDA;
    __shared__ __align__(16) unsigned short As[2 * ASZ];
    const int tid = threadIdx.x;
    const int lane = tid & 63, w = tid >> 6;
    const int quad = lane >> 4, l16 = lane & 15;
    const int n_tile = blockIdx.x, m_tile = blockIdx.y;
    const int g = m_tile >> 3, iq = m_tile & 7;
    const int n0 = n_tile * 512;

    const int brow = tid >> 2;
    const int k8 = (tid & 3) * 16;
    const int bi = iq * 4 + (brow >> 5), bj = brow & 31;
    const float rx = pos[(g * GSZ + bj) * 2 + 0] - pos[(g * GSZ + bi) * 2 + 0];
    const float ry = pos[(g * GSZ + bj) * 2 + 1] - pos[(g * GSZ + bi) * 2 + 1];
    const float* hrow = &Hpartf[(size_t)(g * GSZ + bj) * PRE];

    auto BUILD = [&](int k0i, unsigned short* dst) {
        const int k0 = k0i * 64;
        const float4* hp = (const float4*)(hrow + k0 + k8);
        const float4* wx = (const float4*)(Wcx + k0 + k8);
        const float4* wy = (const float4*)(Wcy + k0 + k8);
        bf8pack o[2];
#pragma unroll
        for (int q = 0; q < 2; ++q) {
            float4 ha = hp[q * 2], hb = hp[q * 2 + 1];
            float4 xa = wx[q * 2], xb = wx[q * 2 + 1];
            float4 ya = wy[q * 2], yb = wy[q * 2 + 1];
            o[q].s[0] = f2bf(fmaxf(ha.x + rx * xa.x + ry * ya.x, 0.f));
            o[q].s[1] = f2bf(fmaxf(ha.y + rx * xa.y + ry * ya.y, 0.f));
            o[q].s[2] = f2bf(fmaxf(ha.z + rx * xa.z + ry * ya.z, 0.f));
            o[q].s[3] = f2bf(fmaxf(ha.w + rx * xa.w + ry * ya.w, 0.f));
            o[q].s[4] = f2bf(fmaxf(hb.x + rx * xb.x + ry * yb.x, 0.f));
            o[q].s[5] = f2bf(fmaxf(hb.y + rx * xb.y + ry * yb.y, 0.f));
            o[q].s[6] = f2bf(fmaxf(hb.z + rx * xb.z + ry * yb.z, 0.f));
            o[q].s[7] = f2bf(fmaxf(hb.w + rx * xb.w + ry * yb.w, 0.f));
        }
        *(uint4*)&dst[brow * LDA + k8] = o[0].v;
        *(uint4*)&dst[brow * LDA + k8 + 8] = o[1].v;
    };

    f32x4 acc[8][4];
#pragma unroll
    for (int mt = 0; mt < 8; ++mt)
#pragma unroll
        for (int nt = 0; nt < 4; ++nt) acc[mt][nt] = (f32x4)0.f;

    BUILD(0, As);
    for (int k0i = 0; k0i < 8; ++k0i) {
        unsigned short* cur = As + (k0i & 1) * ASZ;
        __syncthreads();
        __builtin_amdgcn_s_setprio(1);
#pragma unroll
        for (int ks = 0; ks < 2; ++ks) {
            bf16x8 bfr[4];
#pragma unroll
            for (int nt = 0; nt < 4; ++nt) {
                int cg = n_tile * 32 + w * 4 + nt;
                int ksg = k0i * 2 + ks;
                bfr[nt] = *(const bf16x8*)&W2pk[((size_t)(cg * 16 + ksg) * 64 + lane) * 8];
            }
#pragma unroll
            for (int mt = 0; mt < 8; ++mt) {
                bf16x8 af = *(const bf16x8*)&cur[(mt * 16 + l16) * LDA + ks * 32 + quad * 8];
#pragma unroll
                for (int nt = 0; nt < 4; ++nt)
                    acc[mt][nt] = __builtin_amdgcn_mfma_f32_16x16x32_bf16(af, bfr[nt], acc[mt][nt], 0, 0, 0);
            }
        }
        __builtin_amdgcn_s_setprio(0);
        if (k0i < 7) BUILD(k0i + 1, As + ((k0i + 1) & 1) * ASZ);
    }

#pragma unroll
    for (int il = 0; il < 4; ++il)
#pragma unroll
    for (int nt = 0; nt < 4; ++nt) {
        float u = -1e30f;
#pragma unroll
        for (int p = 0; p < 2; ++p)
#pragma unroll
            for (int r = 0; r < 4; ++r) u = fmaxf(u, acc[il * 2 + p][nt][r]);
        u = fmaxf(u, __shfl_xor(u, 16));
        u = fmaxf(u, __shfl_xor(u, 32));
        if (lane < 16) {
            int col = n0 + w * 64 + nt * 16 + l16;
            int gu = m_tile * 4 + il;
            Abf[(size_t)gu * AK + H + col] = f2bf(fmaxf(u + b2[col], 0.f));
        }
    }
}

// ---------------------------------------------------------------- launch
extern "C" void kernel_launch(void* const* d_in, const int* in_sizes, int n_in,
                              void* d_out, int out_size, void* d_ws, size_t ws_size,
                              hipStream_t stream)
{
    const float* last_pos     = (const float*)d_in[0];
    const float* last_pos_rel = (const float*)d_in[1];
    const float* hh           = (const float*)d_in[2];
    const float* ch           = (const float*)d_in[3];
    const float* ptr_rel      = (const float*)d_in[4];
    const float* Wih  = (const float*)d_in[6];
    const float* Whh  = (const float*)d_in[7];
    const float* bih  = (const float*)d_in[8];
    const float* bhh  = (const float*)d_in[9];
    const float* Wse  = (const float*)d_in[10];
    const float* bse  = (const float*)d_in[11];
    const float* Wpos = (const float*)d_in[12];
    const float* bpos = (const float*)d_in[13];
    const float* Wp   = (const float*)d_in[14];
    const float* bp   = (const float*)d_in[15];
    const float* W1   = (const float*)d_in[16];
    const float* b1   = (const float*)d_in[17];
    const float* W2   = (const float*)d_in[18];
    const float* b2   = (const float*)d_in[19];
    const float* Wm1  = (const float*)d_in[20];
    const float* bm1  = (const float*)d_in[21];
    const float* Wm2  = (const float*)d_in[22];
    const float* bm2  = (const float*)d_in[23];

    float* ws     = (float*)d_ws;
    unsigned short* Ahpk = (unsigned short*)ws;  // 128KB (t=0 gate-A)
    float* cbuf   = ws + BATCH * H;           // 65536
    float* pos    = cbuf + BATCH * H;         // 1024 (padded)
    float* Hpartf = pos + 1024;               // 262144
    float* Wcx    = Hpartf + BATCH * PRE;     // 512
    float* Wcy    = Wcx + PRE;                // 512
    float* biash  = Wcy + PRE;                // 512
    float* bx     = biash + PRE;              // 512
    float* Wx0    = bx + 512;                 // 512
    float* Wx1    = Wx0 + 512;                // 512
    unsigned short* ub    = (unsigned short*)(Wx1 + 512);
    unsigned short* Abf   = ub;                         // 512*1152
    unsigned short* dhpk  = Abf + (size_t)BATCH * AK;   // 512*1024 (fragment-packed, R14)
    unsigned short* W2pk  = dhpk + (size_t)BATCH * MLPD;
    unsigned short* Wm1pk = W2pk + (size_t)BOT * PRE;
    unsigned short* Wm2pk = Wm1pk + (size_t)MLPD * AK;
    unsigned short* W1pk  = Wm2pk + (size_t)H * MLPD;   // 512*128 (packed)
    unsigned short* Whpk  = W1pk + (size_t)PRE * H;     // 512*128 (packed)

    float* out  = (float*)d_out;
    float* loss = out + SEQ * BATCH * 2;

    prep_kernel<<<(PREP_TOT + 255) / 256, 256, 0, stream>>>(
        W2, Wm1, Wm2, W1, Wp, bp, b1, ch, hh, last_pos, Wih, Whh, bih, bhh, Wse, bse,
        W2pk, Wm1pk, Wm2pk, W1pk, Wcx, Wcy, biash, cbuf, Ahpk, pos, Whpk, Wx0, Wx1, bx, loss);

    // step 0 LSTM (gate-A from prep-packed hh)
    lstm_hpart<<<BATCH / LROWS, 512, 0, stream>>>(
        last_pos_rel, ptr_rel, Whpk, Wx0, Wx1, bx, Wpos, bpos, W1pk, biash,
        Ahpk, cbuf, Abf, Hpartf, pos, out, loss);

    for (int t = 0; t < SEQ - 1; t++) {
        // pool(t): fused x1-build + GEMM + max_j
        pool_fused<<<dim3(2, 128), 512, 0, stream>>>(Hpartf, pos, Wcx, Wcy, W2pk, b2, Abf);
        // mlp1(t): dh -> fragment-packed dhpk (MODE 3, R14)
        gemm_splitk_pk<64, 32, 2, 2, 3><<<dim3(MLPD / 32, BATCH / 64), 256, 0, stream>>>(
            Abf, AK, Wm1pk, AK, bm1, nullptr, dhpk, MLPD);
        // mlp2(t) + lstm(t+1) fused (R14): h in LDS, no Ahpk round-trip, -1 dispatch
        mlp2_lstm<<<BATCH / LROWS, 512, 0, stream>>>(
            t + 1, dhpk, Wm2pk, bm2,
            ptr_rel + t * BATCH * 2, ptr_rel + (t + 1) * BATCH * 2,
            Whpk, Wx0, Wx1, bx, Wpos, bpos, W1pk, biash,
            cbuf, Abf, Hpartf, pos, out + (t + 1) * BATCH * 2, loss);
    }
}

// Round 15
// 573.907 us; speedup vs baseline: 3.1459x; 1.1238x over previous
//
#include <hip/hip_runtime.h>
#include <math.h>

#define BATCH 512
#define NG 16
#define GSZ 32
#define H 128
#define E 64
#define PRE 512
#define BOT 1024
#define MLPD 1024
#define SEQ 12
#define AK 1152   // Abf row length = H + BOT

typedef __attribute__((ext_vector_type(8))) short bf16x8;
typedef __attribute__((ext_vector_type(4))) float f32x4;

union bf8pack { ushort s[8]; uint4 v; };

__device__ __forceinline__ unsigned short f2bf(float f) {
    unsigned u = __float_as_uint(f);
    u += 0x7FFF + ((u >> 16) & 1);   // round-to-nearest-even
    return (unsigned short)(u >> 16);
}

__device__ __forceinline__ uint4 pack8(const float* s) {
    float4 a = *(const float4*)s, b = *(const float4*)(s + 4);
    bf8pack o;
    o.s[0] = f2bf(a.x); o.s[1] = f2bf(a.y); o.s[2] = f2bf(a.z); o.s[3] = f2bf(a.w);
    o.s[4] = f2bf(b.x); o.s[5] = f2bf(b.y); o.s[6] = f2bf(b.z); o.s[7] = f2bf(b.w);
    return o.v;
}

#define GLB(p) ((const __attribute__((address_space(1))) unsigned int*)(p))
#define LDS(p) ((__attribute__((address_space(3))) unsigned int*)(p))

// ---------------------------------------------------------------- one-shot prep (R13, 8-wide)
#define U0 ((BOT * PRE) / 8)     /* W2pk   */
#define U1 ((MLPD * AK) / 8)     /* Wm1pk  */
#define U2 ((H * MLPD) / 8)      /* Wm2pk  */
#define U3 ((PRE * H) / 8)       /* W1pk   */
#define U4 (PRE)                 /* wc (scalar) */
#define U5 ((BATCH * H) / 4)     /* cbuf float4 copy */
#define U5b ((BATCH * H) / 8)    /* Ahpk pack of hh (t=0 gate-A) */
#define U6 (BATCH * 2)           /* pos (scalar) */
#define U7 ((512 * 128) / 8)     /* Whpk   */
#define U8 (512)                 /* Wx0/Wx1/bx */
#define PREP_TOT (U0 + U1 + U2 + U3 + U4 + U5 + U5b + U6 + U7 + U8 + 1)

__global__ void prep_kernel(
    const float* __restrict__ W2, const float* __restrict__ Wm1,
    const float* __restrict__ Wm2, const float* __restrict__ W1,
    const float* __restrict__ Wp, const float* __restrict__ bp, const float* __restrict__ b1,
    const float* __restrict__ ch, const float* __restrict__ hh, const float* __restrict__ last_pos,
    const float* __restrict__ Wih, const float* __restrict__ Whh,
    const float* __restrict__ bih, const float* __restrict__ bhh,
    const float* __restrict__ Wse, const float* __restrict__ bse,
    unsigned short* __restrict__ W2pk, unsigned short* __restrict__ Wm1pk,
    unsigned short* __restrict__ Wm2pk, unsigned short* __restrict__ W1pk,
    float* __restrict__ Wcx, float* __restrict__ Wcy, float* __restrict__ biash,
    float* __restrict__ cbuf, unsigned short* __restrict__ Ahpk, float* __restrict__ pos,
    unsigned short* __restrict__ Whpk,
    float* __restrict__ Wx0, float* __restrict__ Wx1, float* __restrict__ bx,
    float* __restrict__ loss)
{
    long idx = (long)blockIdx.x * 256 + threadIdx.x;
    if (idx < U0) {
        int u = (int)idx;
        int lane = u & 63, rest = u >> 6;
        int ksg = rest & 15, cg = rest >> 4;
        int col = cg * 16 + (lane & 15);
        int kk = ksg * 32 + (lane >> 4) * 8;
        *(uint4*)&W2pk[(size_t)u * 8] = pack8(&W2[(size_t)col * PRE + kk]);
        return;
    }
    idx -= U0;
    if (idx < U1) {
        int u = (int)idx;
        int lane = u & 63, rest = u >> 6;
        int ksg = rest % 36, cg = rest / 36;
        int col = cg * 16 + (lane & 15);
        int k = ksg * 32 + (lane >> 4) * 8;
        *(uint4*)&Wm1pk[(size_t)u * 8] = pack8(&Wm1[(size_t)col * AK + k]);
        return;
    }
    idx -= U1;
    if (idx < U2) {
        int u = (int)idx;
        int lane = u & 63, rest = u >> 6;
        int ksg = rest & 31, cg = rest >> 5;
        int col = cg * 16 + (lane & 15);
        int k = ksg * 32 + (lane >> 4) * 8;
        *(uint4*)&Wm2pk[(size_t)u * 8] = pack8(&Wm2[(size_t)col * MLPD + k]);
        return;
    }
    idx -= U2;
    if (idx < U3) {
        int u = (int)idx;
        int l16 = u & 15, quad = (u >> 4) & 3, nt = (u >> 6) & 3, ks = (u >> 8) & 3, w = u >> 10;
        int col = w * 64 + nt * 16 + l16;
        int k = ks * 32 + quad * 8;
        *(uint4*)&W1pk[(size_t)u * 8] = pack8(&W1[col * 192 + E + k]);
        return;
    }
    idx -= U3;
    if (idx < U4) {
        int p = (int)idx;
        float sx = 0.f, sy = 0.f, sb = 0.f;
#pragma unroll 8
        for (int e = 0; e < E; ++e) {
            float w = W1[p * 192 + e];
            sx += w * Wp[e * 2 + 0];
            sy += w * Wp[e * 2 + 1];
            sb += w * bp[e];
        }
        Wcx[p] = sx; Wcy[p] = sy; biash[p] = b1[p] + sb;
        return;
    }
    idx -= U4;
    if (idx < U5) { ((float4*)cbuf)[idx] = ((const float4*)ch)[idx]; return; }
    idx -= U5;
    if (idx < U5b) {
        int u = (int)idx;
        int lane = u & 63, rest = u >> 6;
        int ks = rest & 3, rowtile = rest >> 2;
        int row = rowtile * 16 + (lane & 15);
        int k = ks * 32 + (lane >> 4) * 8;
        *(uint4*)&Ahpk[(size_t)u * 8] = pack8(&hh[(size_t)row * H + k]);
        return;
    }
    idx -= U5b;
    if (idx < U6) { pos[idx] = last_pos[idx]; return; }
    idx -= U6;
    if (idx < U7) {
        int u = (int)idx;
        int l16 = u & 15, quad = (u >> 4) & 3, ks = (u >> 6) & 3, w = (u >> 8) & 7, g = u >> 11;
        int col = g * 128 + w * 16 + l16;
        int k = ks * 32 + quad * 8;
        *(uint4*)&Whpk[(size_t)u * 8] = pack8(&Whh[(size_t)col * H + k]);
        return;
    }
    idx -= U7;
    if (idx < U8) {
        int u = (int)idx;
        float sx = 0.f, sy = 0.f, sb = 0.f;
#pragma unroll 8
        for (int e = 0; e < E; ++e) {
            float w = Wih[u * E + e];
            sx += w * Wse[e * 2 + 0];
            sy += w * Wse[e * 2 + 1];
            sb += w * bse[e];
        }
        Wx0[u] = sx; Wx1[u] = sy; bx[u] = sb + bih[u] + bhh[u];
        return;
    }
    idx -= U8;
    if (idx == 0) *loss = 0.0f;
}

// ---------------------------------------------------------------- lstm body (shared)
__device__ __forceinline__ void lstm_body(
    int s, int r0, int tid, int lane, int w, int quad, int l16,
    unsigned short* hmb /*gate-A in LDS*/, unsigned short* hnb, float* hnf, float* lred,
    const float* relin, const float* gt,
    const unsigned short* Whpk,
    const float* Wx0, const float* Wx1, const float* bx,
    const float* Wpos, const float* bpos,
    const unsigned short* W1pk, const float* biash,
    float* cbuf, unsigned short* Abf, float* Hpartf,
    float* pos, float* traj, float* loss)
{
    constexpr int LDHB = 136;
    constexpr int LDHF = 129;

    // ---- gate GEMM (K=128): A from LDS hmb ----
    f32x4 acc[4];
#pragma unroll
    for (int g4 = 0; g4 < 4; ++g4) acc[g4] = (f32x4)0.f;
#pragma unroll
    for (int ks = 0; ks < 4; ++ks) {
        bf16x8 af = *(const bf16x8*)&hmb[l16 * LDHB + ks * 32 + quad * 8];
#pragma unroll
        for (int gate = 0; gate < 4; ++gate) {
            bf16x8 bf = *(const bf16x8*)&Whpk[((size_t)((gate * 8 + w) * 4 + ks) * 64 + lane) * 8];
            acc[gate] = __builtin_amdgcn_mfma_f32_16x16x32_bf16(af, bf, acc[gate], 0, 0, 0);
        }
    }

    // ---- nonlinearity + c update ----
    {
        int u = w * 16 + l16;
        float wx0[4], wx1[4], bxv[4];
#pragma unroll
        for (int gate = 0; gate < 4; ++gate) {
            int col = gate * 128 + u;
            wx0[gate] = Wx0[col]; wx1[gate] = Wx1[col]; bxv[gate] = bx[col];
        }
#pragma unroll
        for (int r = 0; r < 4; ++r) {
            int row = quad * 4 + r;
            int b = r0 + row;
            float rx = relin[b * 2 + 0], ry = relin[b * 2 + 1];
            float i_ = acc[0][r] + rx * wx0[0] + ry * wx1[0] + bxv[0];
            float f_ = acc[1][r] + rx * wx0[1] + ry * wx1[1] + bxv[1];
            float g_ = acc[2][r] + rx * wx0[2] + ry * wx1[2] + bxv[2];
            float o_ = acc[3][r] + rx * wx0[3] + ry * wx1[3] + bxv[3];
            float ig = 1.0f / (1.0f + expf(-i_));
            float fg = 1.0f / (1.0f + expf(-f_));
            float gg = tanhf(g_);
            float og = 1.0f / (1.0f + expf(-o_));
            float c = fg * cbuf[(size_t)b * H + u] + ig * gg;
            cbuf[(size_t)b * H + u] = c;
            float h = og * tanhf(c);
            hnb[row * LDHB + u] = f2bf(h);
            hnf[row * LDHF + u] = h;
            Abf[(size_t)b * AK + u] = f2bf(h);
        }
    }
    __syncthreads();

    // ---- Hpart GEMM (dead at last step) ----
    if (s < SEQ - 1) {
        f32x4 acc2[4];
#pragma unroll
        for (int nt = 0; nt < 4; ++nt) acc2[nt] = (f32x4)0.f;
#pragma unroll
        for (int ks = 0; ks < 4; ++ks) {
            bf16x8 af = *(const bf16x8*)&hnb[l16 * LDHB + ks * 32 + quad * 8];
#pragma unroll
            for (int nt = 0; nt < 4; ++nt) {
                bf16x8 bfr = *(const bf16x8*)&W1pk[((size_t)((w * 4 + ks) * 4 + nt) * 64 + lane) * 8];
                acc2[nt] = __builtin_amdgcn_mfma_f32_16x16x32_bf16(af, bfr, acc2[nt], 0, 0, 0);
            }
        }
#pragma unroll
        for (int nt = 0; nt < 4; ++nt) {
            int col = w * 64 + nt * 16 + l16;
            float bv = biash[col];
#pragma unroll
            for (int r = 0; r < 4; ++r) {
                int row = quad * 4 + r;
                Hpartf[(size_t)(r0 + row) * PRE + col] = acc2[nt][r] + bv;
            }
        }
    }

    // ---- rel_pos / curr_pos / traj / loss ----
    {
        int row = tid >> 5, o = (tid >> 4) & 1, seg = tid & 15;
        const float* wr = Wpos + o * H + seg * 8;
        const float* hr = &hnf[row * LDHF + seg * 8];
        float acc3 = 0.f;
#pragma unroll
        for (int k = 0; k < 8; ++k) acc3 += wr[k] * hr[k];
        acc3 += __shfl_xor(acc3, 1);
        acc3 += __shfl_xor(acc3, 2);
        acc3 += __shfl_xor(acc3, 4);
        acc3 += __shfl_xor(acc3, 8);
        acc3 += bpos[o];
        int b = r0 + row;
        float d = acc3 - gt[b * 2 + o];
        if (seg == 0) {
            float lp = pos[b * 2 + o];
            pos[b * 2 + o] = acc3 + lp;
            traj[b * 2 + o] = acc3;
        }
        float part = (seg == 0) ? d * d : 0.f;
        part += __shfl_xor(part, 16);
        part += __shfl_xor(part, 32);
        if (lane == 0) lred[w] = part;
        __syncthreads();
        if (tid == 0) {
            float s2 = 0.f;
#pragma unroll
            for (int i = 0; i < 8; ++i) s2 += lred[i];
            atomicAdd(loss, s2 * (1.0f / 1024.0f));
        }
    }
}

// ---------------------------------------------------------------- standalone LSTM (t=0 only)
#define LROWS 16
__global__ __launch_bounds__(512) void lstm_hpart(
    const float* __restrict__ relin, const float* __restrict__ gt,
    const unsigned short* __restrict__ Whpk,
    const float* __restrict__ Wx0, const float* __restrict__ Wx1, const float* __restrict__ bx,
    const float* __restrict__ Wpos, const float* __restrict__ bpos,
    const unsigned short* __restrict__ W1pk, const float* __restrict__ biash,
    const unsigned short* __restrict__ Ahpk, float* __restrict__ cbuf,
    unsigned short* __restrict__ Abf, float* __restrict__ Hpartf,
    float* __restrict__ pos, float* __restrict__ traj, float* __restrict__ loss)
{
    constexpr int LDHB = 136;
    constexpr int LDHF = 129;
    __shared__ __align__(16) unsigned short hmb[LROWS * LDHB];
    __shared__ __align__(16) unsigned short hnb[LROWS * LDHB];
    __shared__ float hnf[LROWS * LDHF];
    __shared__ float lred[8];
    const int blk = blockIdx.x, tid = threadIdx.x;
    const int lane = tid & 63, w = tid >> 6;
    const int quad = lane >> 4, l16 = lane & 15;

    for (int e2 = tid; e2 < LROWS * H / 8; e2 += 512) {
        int lane2 = e2 & 63, ks = e2 >> 6;
        int row = lane2 & 15, k = ks * 32 + (lane2 >> 4) * 8;
        *(uint4*)&hmb[row * LDHB + k] = *(const uint4*)&Ahpk[((size_t)(blk * 4 + ks) * 64 + lane2) * 8];
    }
    __syncthreads();

    lstm_body(0, blk * LROWS, tid, lane, w, quad, l16, hmb, hnb, hnf, lred,
              relin, gt, Whpk, Wx0, Wx1, bx, Wpos, bpos, W1pk, biash,
              cbuf, Abf, Hpartf, pos, traj, loss);
}

// ---------------------------------------------------------------- fused MLP2 + LSTM(s) (R14)
__global__ __launch_bounds__(512) void mlp2_lstm(
    int s,
    const unsigned short* __restrict__ dhpk,
    const unsigned short* __restrict__ Wm2pk, const float* __restrict__ bm2,
    const float* __restrict__ relin, const float* __restrict__ gt,
    const unsigned short* __restrict__ Whpk,
    const float* __restrict__ Wx0, const float* __restrict__ Wx1, const float* __restrict__ bx,
    const float* __restrict__ Wpos, const float* __restrict__ bpos,
    const unsigned short* __restrict__ W1pk, const float* __restrict__ biash,
    float* __restrict__ cbuf,
    unsigned short* __restrict__ Abf, float* __restrict__ Hpartf,
    float* __restrict__ pos, float* __restrict__ traj, float* __restrict__ loss)
{
    constexpr int LDHB = 136;
    constexpr int LDHF = 129;
    __shared__ __align__(16) unsigned short hmb[LROWS * LDHB];
    __shared__ __align__(16) unsigned short hnb[LROWS * LDHB];
    __shared__ float hnf[LROWS * LDHF];
    __shared__ float lred[8];
    const int blk = blockIdx.x, tid = threadIdx.x;
    const int lane = tid & 63, w = tid >> 6;
    const int quad = lane >> 4, l16 = lane & 15;

    // ---- phase A: mlp2 — wave w owns cols w*16..w*16+16, K=1024 ----
    f32x4 acc0 = (f32x4)0.f;
#pragma unroll 8
    for (int ki = 0; ki < 32; ++ki) {
        bf16x8 af = *(const bf16x8*)&dhpk[((size_t)(blk * 32 + ki) * 64 + lane) * 8];
        bf16x8 bf = *(const bf16x8*)&Wm2pk[((size_t)(w * 32 + ki) * 64 + lane) * 8];
        acc0 = __builtin_amdgcn_mfma_f32_16x16x32_bf16(af, bf, acc0, 0, 0, 0);
    }
    {
        int u = w * 16 + l16;
        float bv = bm2[u];
#pragma unroll
        for (int r = 0; r < 4; ++r)
            hmb[(quad * 4 + r) * LDHB + u] = f2bf(fmaxf(acc0[r] + bv, 0.f));
    }
    __syncthreads();

    lstm_body(s, blk * LROWS, tid, lane, w, quad, l16, hmb, hnb, hnf, lred,
              relin, gt, Whpk, Wx0, Wx1, bx, Wpos, bpos, W1pk, biash,
              cbuf, Abf, Hpartf, pos, traj, loss);
}

// ---------------------------------------------------------------- split-K bf16 MFMA GEMM, packed-B (R12 dbuf)
// R15: red padded to BN+1 (912K/dispatch 4-way bank conflicts on partial stores).
// MODE 1: Cb row-major bf16 | MODE 2: Cf row-major f32 | MODE 3: Cb fragment-packed
template <int BM, int BN, int KW, int NW, int MODE>
__global__ __launch_bounds__(256) void gemm_splitk_pk(
    const unsigned short* __restrict__ A, int lda,
    const unsigned short* __restrict__ Bpk, int K,
    const float* __restrict__ bias,
    float* __restrict__ Cf, unsigned short* __restrict__ Cb, int ldc)
{
    constexpr int MT = BM / 16;
    constexpr int NT = BN / (16 * NW);
    constexpr int ABUF = KW * BM * 64;
    constexpr int BNP = BN + 1;            // R15: +1 pad kills 4-way write conflicts
    __shared__ __align__(16) unsigned short As[2 * ABUF];
    __shared__ float red[KW * BM * BNP];
    int tid = threadIdx.x;
    int lane = tid & 63, w = tid >> 6;
    int kslice = w / NW, nslice = w % NW;
    int gtid = tid & (NW * 64 - 1);
    int quad = lane >> 4, l16 = lane & 15;
    int m0 = blockIdx.y * BM, n0 = blockIdx.x * BN;
    const int KC = K / KW;
    const int NK = KC / 64;
    const int KSGT = K >> 5;
    const int cgbase = (n0 + nslice * (BN / NW)) >> 4;

    auto STAGE = [&](int ki, int bo) {
        int kb = kslice * KC + ki * 64;
#pragma unroll
        for (int u = 0; u < BM / (8 * NW); ++u) {
            int c = u * NW * 64 + gtid;
            __builtin_amdgcn_global_load_lds(
                GLB(A + (size_t)(m0 + (c >> 3)) * lda + kb + (c & 7) * 8),
                LDS(&As[bo + kslice * BM * 64 + c * 8]), 16, 0, 0);
        }
    };

    f32x4 acc[MT][NT];
#pragma unroll
    for (int mt = 0; mt < MT; ++mt)
#pragma unroll
        for (int nt = 0; nt < NT; ++nt) acc[mt][nt] = (f32x4)0.f;

    STAGE(0, 0);
    for (int ki = 0; ki < NK; ++ki) {
        int bo = (ki & 1) * ABUF;
        int kgbase = (kslice * KC + ki * 64) >> 5;
        __syncthreads();
#pragma unroll
        for (int ks = 0; ks < 2; ++ks) {
            bf16x8 af[MT], bfr[NT];
#pragma unroll
            for (int mt = 0; mt < MT; ++mt)
                af[mt] = *(const bf16x8*)&As[bo + kslice * BM * 64 + (mt * 16 + l16) * 64 + ks * 32 + quad * 8];
#pragma unroll
            for (int nt = 0; nt < NT; ++nt)
                bfr[nt] = *(const bf16x8*)&Bpk[((size_t)((cgbase + nt) * KSGT + kgbase + ks) * 64 + lane) * 8];
#pragma unroll
            for (int mt = 0; mt < MT; ++mt)
#pragma unroll
                for (int nt = 0; nt < NT; ++nt)
                    acc[mt][nt] = __builtin_amdgcn_mfma_f32_16x16x32_bf16(af[mt], bfr[nt], acc[mt][nt], 0, 0, 0);
        }
        if (ki + 1 < NK) STAGE(ki + 1, ((ki + 1) & 1) * ABUF);
    }

#pragma unroll
    for (int mt = 0; mt < MT; ++mt)
#pragma unroll
    for (int nt = 0; nt < NT; ++nt) {
#pragma unroll
        for (int r = 0; r < 4; ++r) {
            int row = mt * 16 + quad * 4 + r;
            int col = nslice * (BN / NW) + nt * 16 + l16;
            red[kslice * BM * BNP + row * BNP + col] = acc[mt][nt][r];
        }
    }
    __syncthreads();

#pragma unroll
    for (int o = 0; o < BM * BN / 256; ++o) {
        int e = o * 256 + tid;
        int row = e / BN, col = e % BN;
        float s = 0.f;
#pragma unroll
        for (int k = 0; k < KW; ++k) s += red[k * BM * BNP + row * BNP + col];
        float v = fmaxf(s + bias[n0 + col], 0.f);
        if (MODE == 1) {
            Cb[(size_t)(m0 + row) * ldc + n0 + col] = f2bf(v);
        } else if (MODE == 2) {
            Cf[(size_t)(m0 + row) * ldc + n0 + col] = v;
        } else {
            int gr = m0 + row, gc = n0 + col;
            int rowtile = gr >> 4, l16p = gr & 15;
            int ksv = gc >> 5, quadp = (gc >> 3) & 3, ep = gc & 7;
            int lanep = quadp * 16 + l16p;
            Cb[((size_t)(rowtile * (ldc >> 5) + ksv) * 64 + lanep) * 8 + ep] = f2bf(v);
        }
    }
}

// ---------------------------------------------------------------- fused x1-build + pool GEMM + max_j
// R15: M-split — 64 A-rows/block (2 i x 32 j), grid (2 n_tiles, 256 m_tiles) = 512
// blocks -> 2 blocks/CU co-resident (was 1; zero cross-block latency overlap).
// Total build + MFMA work unchanged; per-output K-order and max-order unchanged.
__global__ __launch_bounds__(512) void pool_fused(
    const float* __restrict__ Hpartf, const float* __restrict__ pos,
    const float* __restrict__ Wcx, const float* __restrict__ Wcy,
    const unsigned short* __restrict__ W2pk,
    const float* __restrict__ b2, unsigned short* __restrict__ Abf)
{
    constexpr int LDA = 72;    // row stride 144B -> 2-way bank aliasing (free, m136)
    constexpr int ASZ = 64 * LDA;
    __shared__ __align__(16) unsigned short As[2 * ASZ];   // 18.4 KB double-buffered
    const int tid = threadIdx.x;
    const int lane = tid & 63, w = tid >> 6;       // 8 waves
    const int quad = lane >> 4, l16 = lane & 15;
    const int n_tile = blockIdx.x, m_tile2 = blockIdx.y;   // m_tile2: 0..255
    const int g = m_tile2 >> 4, iq2 = m_tile2 & 15;        // i-pair index
    const int n0 = n_tile * 512;

    // per-thread build coords: 512 thr = 64 rows x 8 col-slabs of 8
    const int brow = tid >> 3;                 // 0..63
    const int k8 = (tid & 7) * 8;              // col base within K-step
    const int bi = iq2 * 2 + (brow >> 5), bj = brow & 31;
    const float rx = pos[(g * GSZ + bj) * 2 + 0] - pos[(g * GSZ + bi) * 2 + 0];
    const float ry = pos[(g * GSZ + bj) * 2 + 1] - pos[(g * GSZ + bi) * 2 + 1];
    const float* hrow = &Hpartf[(size_t)(g * GSZ + bj) * PRE];

    auto BUILD = [&](int k0i, unsigned short* dst) {
        const int k0 = k0i * 64;
        const float* hp = hrow + k0 + k8;
        const float* wx = Wcx + k0 + k8;
        const float* wy = Wcy + k0 + k8;
        float4 ha = *(const float4*)hp, hb = *(const float4*)(hp + 4);
        float4 xa = *(const float4*)wx, xb = *(const float4*)(wx + 4);
        float4 ya = *(const float4*)wy, yb = *(const float4*)(wy + 4);
        bf8pack o;
        o.s[0] = f2bf(fmaxf(ha.x + rx * xa.x + ry * ya.x, 0.f));
        o.s[1] = f2bf(fmaxf(ha.y + rx * xa.y + ry * ya.y, 0.f));
        o.s[2] = f2bf(fmaxf(ha.z + rx * xa.z + ry * ya.z, 0.f));
        o.s[3] = f2bf(fmaxf(ha.w + rx * xa.w + ry * ya.w, 0.f));
        o.s[4] = f2bf(fmaxf(hb.x + rx * xb.x + ry * yb.x, 0.f));
        o.s[5] = f2bf(fmaxf(hb.y + rx * xb.y + ry * yb.y, 0.f));
        o.s[6] = f2bf(fmaxf(hb.z + rx * xb.z + ry * yb.z, 0.f));
        o.s[7] = f2bf(fmaxf(hb.w + rx * xb.w + ry * yb.w, 0.f));
        *(uint4*)&dst[brow * LDA + k8] = o.v;
    };

    f32x4 acc[4][4];
#pragma unroll
    for (int mt = 0; mt < 4; ++mt)
#pragma unroll
        for (int nt = 0; nt < 4; ++nt) acc[mt][nt] = (f32x4)0.f;

    BUILD(0, As);
    for (int k0i = 0; k0i < 8; ++k0i) {
        unsigned short* cur = As + (k0i & 1) * ASZ;
        __syncthreads();                   // build(k0i) visible; mfma(k0i-1) done before buf reuse
        __builtin_amdgcn_s_setprio(1);
#pragma unroll
        for (int ks = 0; ks < 2; ++ks) {
            bf16x8 bfr[4];
#pragma unroll
            for (int nt = 0; nt < 4; ++nt) {
                int cg = n_tile * 32 + w * 4 + nt;
                int ksg = k0i * 2 + ks;
                bfr[nt] = *(const bf16x8*)&W2pk[((size_t)(cg * 16 + ksg) * 64 + lane) * 8];
            }
#pragma unroll
            for (int mt = 0; mt < 4; ++mt) {
                bf16x8 af = *(const bf16x8*)&cur[(mt * 16 + l16) * LDA + ks * 32 + quad * 8];
#pragma unroll
                for (int nt = 0; nt < 4; ++nt)
                    acc[mt][nt] = __builtin_amdgcn_mfma_f32_16x16x32_bf16(af, bfr[nt], acc[mt][nt], 0, 0, 0);
            }
        }
        __builtin_amdgcn_s_setprio(0);
        if (k0i < 7) BUILD(k0i + 1, As + ((k0i + 1) & 1) * ASZ);
    }

    // ---- max over j: rows il*32..il*32+31 live in acc[2il..2il+1] x quad lanes ----
#pragma unroll
    for (int il = 0; il < 2; ++il)
#pragma unroll
    for (int nt = 0; nt < 4; ++nt) {
        float u = -1e30f;
#pragma unroll
        for (int p = 0; p < 2; ++p)
#pragma unroll
            for (int r = 0; r < 4; ++r) u = fmaxf(u, acc[il * 2 + p][nt][r]);
        u = fmaxf(u, __shfl_xor(u, 16));
        u = fmaxf(u, __shfl_xor(u, 32));
        if (lane < 16) {
            int col = n0 + w * 64 + nt * 16 + l16;
            int gu = m_tile2 * 2 + il;
            Abf[(size_t)gu * AK + H + col] = f2bf(fmaxf(u + b2[col], 0.f));
        }
    }
}

// ---------------------------------------------------------------- launch
extern "C" void kernel_launch(void* const* d_in, const int* in_sizes, int n_in,
                              void* d_out, int out_size, void* d_ws, size_t ws_size,
                              hipStream_t stream)
{
    const float* last_pos     = (const float*)d_in[0];
    const float* last_pos_rel = (const float*)d_in[1];
    const float* hh           = (const float*)d_in[2];
    const float* ch           = (const float*)d_in[3];
    const float* ptr_rel      = (const float*)d_in[4];
    const float* Wih  = (const float*)d_in[6];
    const float* Whh  = (const float*)d_in[7];
    const float* bih  = (const float*)d_in[8];
    const float* bhh  = (const float*)d_in[9];
    const float* Wse  = (const float*)d_in[10];
    const float* bse  = (const float*)d_in[11];
    const float* Wpos = (const float*)d_in[12];
    const float* bpos = (const float*)d_in[13];
    const float* Wp   = (const float*)d_in[14];
    const float* bp   = (const float*)d_in[15];
    const float* W1   = (const float*)d_in[16];
    const float* b1   = (const float*)d_in[17];
    const float* W2   = (const float*)d_in[18];
    const float* b2   = (const float*)d_in[19];
    const float* Wm1  = (const float*)d_in[20];
    const float* bm1  = (const float*)d_in[21];
    const float* Wm2  = (const float*)d_in[22];
    const float* bm2  = (const float*)d_in[23];

    float* ws     = (float*)d_ws;
    unsigned short* Ahpk = (unsigned short*)ws;  // 128KB (t=0 gate-A)
    float* cbuf   = ws + BATCH * H;           // 65536
    float* pos    = cbuf + BATCH * H;         // 1024 (padded)
    float* Hpartf = pos + 1024;               // 262144
    float* Wcx    = Hpartf + BATCH * PRE;     // 512
    float* Wcy    = Wcx + PRE;                // 512
    float* biash  = Wcy + PRE;                // 512
    float* bx     = biash + PRE;              // 512
    float* Wx0    = bx + 512;                 // 512
    float* Wx1    = Wx0 + 512;                // 512
    unsigned short* ub    = (unsigned short*)(Wx1 + 512);
    unsigned short* Abf   = ub;                         // 512*1152
    unsigned short* dhpk  = Abf + (size_t)BATCH * AK;   // 512*1024 (fragment-packed)
    unsigned short* W2pk  = dhpk + (size_t)BATCH * MLPD;
    unsigned short* Wm1pk = W2pk + (size_t)BOT * PRE;
    unsigned short* Wm2pk = Wm1pk + (size_t)MLPD * AK;
    unsigned short* W1pk  = Wm2pk + (size_t)H * MLPD;   // 512*128 (packed)
    unsigned short* Whpk  = W1pk + (size_t)PRE * H;     // 512*128 (packed)

    float* out  = (float*)d_out;
    float* loss = out + SEQ * BATCH * 2;

    prep_kernel<<<(PREP_TOT + 255) / 256, 256, 0, stream>>>(
        W2, Wm1, Wm2, W1, Wp, bp, b1, ch, hh, last_pos, Wih, Whh, bih, bhh, Wse, bse,
        W2pk, Wm1pk, Wm2pk, W1pk, Wcx, Wcy, biash, cbuf, Ahpk, pos, Whpk, Wx0, Wx1, bx, loss);

    // step 0 LSTM (gate-A from prep-packed hh)
    lstm_hpart<<<BATCH / LROWS, 512, 0, stream>>>(
        last_pos_rel, ptr_rel, Whpk, Wx0, Wx1, bx, Wpos, bpos, W1pk, biash,
        Ahpk, cbuf, Abf, Hpartf, pos, out, loss);

    for (int t = 0; t < SEQ - 1; t++) {
        // pool(t): fused x1-build + GEMM + max_j — R15: M-split, 512 blocks, 2/CU
        pool_fused<<<dim3(2, 256), 512, 0, stream>>>(Hpartf, pos, Wcx, Wcy, W2pk, b2, Abf);
        // mlp1(t): dh -> fragment-packed dhpk (MODE 3)
        gemm_splitk_pk<64, 32, 2, 2, 3><<<dim3(MLPD / 32, BATCH / 64), 256, 0, stream>>>(
            Abf, AK, Wm1pk, AK, bm1, nullptr, dhpk, MLPD);
        // mlp2(t) + lstm(t+1) fused
        mlp2_lstm<<<BATCH / LROWS, 512, 0, stream>>>(
            t + 1, dhpk, Wm2pk, bm2,
            ptr_rel + t * BATCH * 2, ptr_rel + (t + 1) * BATCH * 2,
            Whpk, Wx0, Wx1, bx, Wpos, bpos, W1pk, biash,
            cbuf, Abf, Hpartf, pos, out + (t + 1) * BATCH * 2, loss);
    }
}